// Round 7
// baseline (180.698 us; speedup 1.0000x reference)
//
#include <hip/hip_runtime.h>
#include <hip/hip_bf16.h>
#include <stdint.h>

typedef float f32x4 __attribute__((ext_vector_type(4)));
typedef __bf16 bf16x8 __attribute__((ext_vector_type(8)));

#define NBH 64      // B*H
#define SS 1024     // SQ == SKV
#define DAUG 160    // augmented head dim 132 padded to 160
#define KAPPA 0.18033688011104293f  // 0.125 * log2(e), folded into Q~

static __device__ __forceinline__ unsigned short f2b(float f) {
  union { float f; uint32_t u; } v; v.f = f;
  return (unsigned short)((v.u + 0x7fffu + ((v.u >> 16) & 1u)) >> 16);
}
static __device__ __forceinline__ float b2f(unsigned short s) {
  union { uint32_t u; float f; } v; v.u = ((uint32_t)s) << 16;
  return v.f;
}

static __device__ __forceinline__ void async16(const void* g, void* l) {
  __builtin_amdgcn_global_load_lds(
      (const __attribute__((address_space(1))) uint32_t*)g,
      (__attribute__((address_space(3))) uint32_t*)l, 16, 0, 0);
}

// DPP max-reduce over 16-lane rows (VALU pipe, no LDS traffic).
template <int CTRL>
static __device__ __forceinline__ float dppmaxstep(float x) {
  int y = __builtin_amdgcn_update_dpp(__builtin_bit_cast(int, x), __builtin_bit_cast(int, x),
                                      CTRL, 0xF, 0xF, false);
  return fmaxf(x, __builtin_bit_cast(float, y));
}
static __device__ __forceinline__ float rowmax16(float x) {
  x = dppmaxstep<0x128>(x);  // row_ror:8
  x = dppmaxstep<0x124>(x);  // row_ror:4
  x = dppmaxstep<0x122>(x);  // row_ror:2
  x = dppmaxstep<0x121>(x);  // row_ror:1
  return x;
}

// ---------------- f32 -> bf16 conversion for 7 tensors ----------------
__global__ void convert7(const float* q, const float* k, const float* v,
                         const float* wq, const float* wk, const float* wv, const float* wo,
                         unsigned short* xq, unsigned short* xk, unsigned short* xv,
                         unsigned short* bwq, unsigned short* bwk, unsigned short* bwv,
                         unsigned short* bwo) {
  const float* s; unsigned short* d; int n;
  switch (blockIdx.y) {
    case 0: s = q;  d = xq;  n = 4194304; break;
    case 1: s = k;  d = xk;  n = 4194304; break;
    case 2: s = v;  d = xv;  n = 4194304; break;
    case 3: s = wq; d = bwq; n = 1048576; break;
    case 4: s = wk; d = bwk; n = 1048576; break;
    case 5: s = wv; d = bwv; n = 1048576; break;
    default: s = wo; d = bwo; n = 1048576; break;
  }
  int n4 = n >> 2;
  for (int i = blockIdx.x * blockDim.x + threadIdx.x; i < n4; i += gridDim.x * blockDim.x) {
    float4 f = ((const float4*)s)[i];
    ushort4 o;
    o.x = f2b(f.x); o.y = f2b(f.y); o.z = f2b(f.z); o.w = f2b(f.w);
    ((ushort4*)d)[i] = o;
  }
}

// ---------------- QKV projection GEMM: Y = X @ W^T, 2-phase dbuf, XCD swizzle --------
__global__ __launch_bounds__(256) void proj_qkv(
    const unsigned short* __restrict__ Xq, const unsigned short* __restrict__ Xk,
    const unsigned short* __restrict__ Xv, const unsigned short* __restrict__ Wqb,
    const unsigned short* __restrict__ Wkb, const unsigned short* __restrict__ Wvb,
    unsigned short* __restrict__ Qt, unsigned short* __restrict__ Kt,
    unsigned short* __restrict__ Vp) {
  // T1 bijective XCD swizzle: 768 blocks, dispatch id n -> orig o so that each
  // XCD (n%8) gets 96 consecutive orig ids (3 full W-panels of 32 blocks each).
  const int n_ = blockIdx.x + 32 * (blockIdx.y + 8 * blockIdx.z);
  const int o_ = (n_ & 7) * 96 + (n_ >> 3);
  const int bx = o_ & 31, by = (o_ >> 5) & 7, z = o_ >> 8;

  const unsigned short* A = (z == 0) ? Xq : (z == 1) ? Xk : Xv;
  const unsigned short* Bw = (z == 0) ? Wqb : (z == 1) ? Wkb : Wvb;
  unsigned short* Dst = (z == 0) ? Qt : (z == 1) ? Kt : Vp;
  const int dstride = (z == 2) ? 64 : DAUG;
  const float sc = (z == 0) ? KAPPA : 1.0f;

  __shared__ unsigned short At[2][128 * 32];
  __shared__ unsigned short Bt[2][128 * 32];

  const int tid = threadIdx.x, wave = tid >> 6, lane = tid & 63;
  const int r15 = lane & 15, g4 = lane >> 4;
  const int i0 = bx * 128, j0 = by * 128;
  const int wm = (wave >> 1) * 64, wn = (wave & 1) * 64;

  auto stage = [&](int k0, int buf) {
#pragma unroll
    for (int c = 0; c < 2; ++c) {
      int ch = (wave * 2 + c) * 64 + lane;
      int row = ch >> 2, cg = ch & 3;
      async16(A + (size_t)(i0 + row) * 1024 + k0 + cg * 8, &At[buf][0] + (wave * 2 + c) * 512);
      async16(Bw + (size_t)(j0 + row) * 1024 + k0 + cg * 8, &Bt[buf][0] + (wave * 2 + c) * 512);
    }
  };

  f32x4 acc[4][4];
#pragma unroll
  for (int m = 0; m < 4; ++m)
#pragma unroll
    for (int n = 0; n < 4; ++n) acc[m][n] = (f32x4){0.f, 0.f, 0.f, 0.f};

  stage(0, 0);
  __syncthreads();

  for (int it = 0; it < 32; ++it) {
    const int cur = it & 1, nxt = cur ^ 1;
    if (it < 31) stage((it + 1) * 32, nxt);
    bf16x8 af[4], bf[4];
#pragma unroll
    for (int m = 0; m < 4; ++m)
      af[m] = *(const bf16x8*)(&At[cur][(wm + m * 16 + r15) * 32 + g4 * 8]);
#pragma unroll
    for (int n = 0; n < 4; ++n)
      bf[n] = *(const bf16x8*)(&Bt[cur][(wn + n * 16 + r15) * 32 + g4 * 8]);
    __builtin_amdgcn_s_setprio(1);
#pragma unroll
    for (int m = 0; m < 4; ++m)
#pragma unroll
      for (int n = 0; n < 4; ++n)
        acc[m][n] = __builtin_amdgcn_mfma_f32_16x16x32_bf16(af[m], bf[n], acc[m][n], 0, 0, 0);
    __builtin_amdgcn_s_setprio(0);
    __syncthreads();
  }

#pragma unroll
  for (int m = 0; m < 4; ++m)
#pragma unroll
    for (int n = 0; n < 4; ++n)
#pragma unroll
      for (int r = 0; r < 4; ++r) {
        int i = i0 + wm + m * 16 + g4 * 4 + r;
        int j = j0 + wn + n * 16 + r15;
        int b = i >> 10, s = i & 1023, h = j >> 6, d = j & 63;
        Dst[(((size_t)b * 16 + h) * SS + s) * dstride + d] = f2b(acc[m][n][r] * sc);
      }
}

// ---------------- output projection GEMM: out = Oh @ Wo^T, 2-phase dbuf, XCD swizzle -----
__global__ __launch_bounds__(256) void gemm_out(const unsigned short* __restrict__ Oh,
                                                const unsigned short* __restrict__ Wob,
                                                float* __restrict__ Out) {
  const int n_ = blockIdx.x + 32 * blockIdx.y;
  const int o_ = (n_ & 7) * 32 + (n_ >> 3);
  const int bx = o_ & 31, by = o_ >> 5;

  __shared__ unsigned short At[2][128 * 32];
  __shared__ unsigned short Bt[2][128 * 32];

  const int tid = threadIdx.x, wave = tid >> 6, lane = tid & 63;
  const int r15 = lane & 15, g4 = lane >> 4;
  const int i0 = bx * 128, j0 = by * 128;
  const int wm = (wave >> 1) * 64, wn = (wave & 1) * 64;

  auto stage = [&](int k0, int buf) {
#pragma unroll
    for (int c = 0; c < 2; ++c) {
      int ch = (wave * 2 + c) * 64 + lane;
      int row = ch >> 2, cg = ch & 3;
      int i = i0 + row, b = i >> 10, s = i & 1023;
      int kcol = k0 + cg * 8, h = kcol >> 6, dd = kcol & 63;
      async16(Oh + (((size_t)b * 16 + h) * SS + s) * 64 + dd, &At[buf][0] + (wave * 2 + c) * 512);
      async16(Wob + (size_t)(j0 + row) * 1024 + k0 + cg * 8, &Bt[buf][0] + (wave * 2 + c) * 512);
    }
  };

  f32x4 acc[4][4];
#pragma unroll
  for (int m = 0; m < 4; ++m)
#pragma unroll
    for (int n = 0; n < 4; ++n) acc[m][n] = (f32x4){0.f, 0.f, 0.f, 0.f};

  stage(0, 0);
  __syncthreads();

  for (int it = 0; it < 32; ++it) {
    const int cur = it & 1, nxt = cur ^ 1;
    if (it < 31) stage((it + 1) * 32, nxt);
    bf16x8 af[4], bf[4];
#pragma unroll
    for (int m = 0; m < 4; ++m)
      af[m] = *(const bf16x8*)(&At[cur][(wm + m * 16 + r15) * 32 + g4 * 8]);
#pragma unroll
    for (int n = 0; n < 4; ++n)
      bf[n] = *(const bf16x8*)(&Bt[cur][(wn + n * 16 + r15) * 32 + g4 * 8]);
    __builtin_amdgcn_s_setprio(1);
#pragma unroll
    for (int m = 0; m < 4; ++m)
#pragma unroll
      for (int n = 0; n < 4; ++n)
        acc[m][n] = __builtin_amdgcn_mfma_f32_16x16x32_bf16(af[m], bf[n], acc[m][n], 0, 0, 0);
    __builtin_amdgcn_s_setprio(0);
    __syncthreads();
  }

#pragma unroll
  for (int m = 0; m < 4; ++m)
#pragma unroll
    for (int n = 0; n < 4; ++n)
#pragma unroll
      for (int r = 0; r < 4; ++r) {
        int i = i0 + wm + m * 16 + g4 * 4 + r;
        int j = j0 + wn + n * 16 + r15;
        Out[(size_t)i * 1024 + j] = acc[m][n][r];
      }
}

// ---------------- rank-34 augmentation via MFMA (merged Q/K via grid.z) ----------------
__global__ __launch_bounds__(256) void aug_dots_mfma2(unsigned short* __restrict__ Qt,
                                                      unsigned short* __restrict__ Kt,
                                                      const float* __restrict__ relk,
                                                      const float* __restrict__ relq) {
  const int z = blockIdx.z;
  unsigned short* T = z ? Kt : Qt;
  const float* rel = z ? relq : relk;
  const int cbase = z ? 98 : 64;
  const int bh = blockIdx.y, h = bh & 15, s0 = blockIdx.x * 128;
  const int tid = threadIdx.x, wave = tid >> 6, lane = tid & 63;
  const int r15 = lane & 15, g4 = lane >> 4;

  __shared__ unsigned short RL[48 * 72];
  for (int idx = tid; idx < 48 * 64; idx += 256) {
    int r = idx >> 6, d = idx & 63;
    RL[r * 72 + d] = (r < 34) ? f2b(rel[((size_t)h * 34 + r) * 64 + d]) : (unsigned short)0;
  }
  __syncthreads();

  bf16x8 bfr[3][2];
#pragma unroll
  for (int n = 0; n < 3; ++n)
#pragma unroll
    for (int st = 0; st < 2; ++st)
      bfr[n][st] = *(const bf16x8*)(RL + (n * 16 + r15) * 72 + st * 32 + g4 * 8);

  f32x4 acc[2][3];
#pragma unroll
  for (int m = 0; m < 2; ++m)
#pragma unroll
    for (int n = 0; n < 3; ++n) acc[m][n] = (f32x4){0.f, 0.f, 0.f, 0.f};

#pragma unroll
  for (int m = 0; m < 2; ++m) {
    const unsigned short* Arow = T + ((size_t)bh * SS + s0 + wave * 32 + m * 16 + r15) * DAUG;
    bf16x8 a0 = *(const bf16x8*)(Arow + g4 * 8);
    bf16x8 a1 = *(const bf16x8*)(Arow + 32 + g4 * 8);
#pragma unroll
    for (int n = 0; n < 3; ++n) {
      acc[m][n] = __builtin_amdgcn_mfma_f32_16x16x32_bf16(a0, bfr[n][0], acc[m][n], 0, 0, 0);
      acc[m][n] = __builtin_amdgcn_mfma_f32_16x16x32_bf16(a1, bfr[n][1], acc[m][n], 0, 0, 0);
    }
  }

#pragma unroll
  for (int m = 0; m < 2; ++m)
#pragma unroll
    for (int n = 0; n < 3; ++n) {
      int col = n * 16 + r15;
      if (col < 34) {
#pragma unroll
        for (int r = 0; r < 4; ++r) {
          int row = s0 + wave * 32 + m * 16 + g4 * 4 + r;
          T[((size_t)bh * SS + row) * DAUG + cbase + col] = f2b(acc[m][n][r]);
        }
      }
    }
}

// ---------------- pos transpose-copy + zero pad (merged Q/K via grid.z) -------------
__global__ __launch_bounds__(256) void pos_copy2(unsigned short* __restrict__ Qt,
                                                 unsigned short* __restrict__ Kt,
                                                 const float* __restrict__ cpe,
                                                 const float* __restrict__ cpp,
                                                 const float* __restrict__ pe,
                                                 const float* __restrict__ pp) {
  const int z = blockIdx.z;
  unsigned short* T = z ? Kt : Qt;
  const float* Pe = z ? pe : cpe;
  const float* Pp = z ? pp : cpp;
  const int cbase = z ? 64 : 98;
  const float scale = z ? 1.0f : KAPPA;
  const int bh = blockIdx.y, s0 = blockIdx.x * 64;
  const int tid = threadIdx.x;
  __shared__ float PeL[17][65];
  __shared__ float PpL[17][65];

  for (int idx = tid; idx < 17 * 64; idx += 256) {
    int r = idx >> 6, c = idx & 63;
    PeL[r][c] = Pe[((size_t)bh * 17 + r) * SS + s0 + c];
    PpL[r][c] = Pp[((size_t)bh * 17 + r) * SS + s0 + c];
  }
  __syncthreads();

  for (int idx = tid; idx < 4096; idx += 256) {
    int s = idx >> 6, j = idx & 63;
    if (j < 34) {
      float v = (j < 17) ? PeL[j][s] : PpL[j - 17][s];
      T[((size_t)bh * SS + s0 + s) * DAUG + cbase + j] = f2b(v * scale);
    } else if (j < 62) {
      T[((size_t)bh * SS + s0 + s) * DAUG + 132 + (j - 34)] = 0;
    }
  }
}

// ---------------- V' build, transposed: VpT[bh][d 0..79][s] ----------------
__global__ __launch_bounds__(256) void vprime_T(const unsigned short* __restrict__ Vp,
                                                const float* __restrict__ Pe,
                                                const float* __restrict__ Pp,
                                                const float* __restrict__ relv,
                                                unsigned short* __restrict__ VpT) {
  const int bh = blockIdx.y, h = bh & 15, s0 = blockIdx.x * 64;
  const int tid = threadIdx.x;
  __shared__ float PeL[17][65];
  __shared__ float PpL[17][65];
  __shared__ unsigned short VT[64][72];  // [d][s-local]

  for (int idx = tid; idx < 17 * 64; idx += 256) {
    int r = idx >> 6, c = idx & 63;
    PeL[r][c] = Pe[((size_t)bh * 17 + r) * SS + s0 + c];
    PpL[r][c] = Pp[((size_t)bh * 17 + r) * SS + s0 + c];
  }
  __syncthreads();

  const int d = tid & 63, sg = tid >> 6;
  float acc[16];
#pragma unroll
  for (int si = 0; si < 16; ++si) acc[si] = 0.f;
  for (int r = 0; r < 17; ++r) {
    float ve = relv[((size_t)h * 34 + r) * 64 + d];
    float vpv = relv[((size_t)h * 34 + 17 + r) * 64 + d];
#pragma unroll
    for (int si = 0; si < 16; ++si) {
      int s = sg * 16 + si;
      acc[si] += PeL[r][s] * ve + PpL[r][s] * vpv;
    }
  }
#pragma unroll
  for (int si = 0; si < 16; ++si) {
    int s = sg * 16 + si;
    float v = b2f(Vp[((size_t)bh * SS + s0 + s) * 64 + d]) + acc[si];
    VT[d][s] = f2b(v);
  }
  __syncthreads();

  for (int c = tid; c < 512; c += 256) {
    int row = c >> 3, c8 = c & 7;
    uint4 v = *(const uint4*)&VT[row][c8 * 8];
    *(uint4*)(VpT + ((size_t)bh * 80 + row) * 1024 + s0 + c8 * 8) = v;
  }
  if (tid < 128) {
    int row = 64 + (tid >> 3), c8 = tid & 7;
    uint32_t w = (row == 64) ? 0x3F803F80u : 0u;
    uint4 v = {w, w, w, w};
    *(uint4*)(VpT + ((size_t)bh * 80 + row) * 1024 + s0 + c8 * 8) = v;
  }
}

// ---------------- flash attention v6: QB=256, 8 waves x 32 q-rows ----------------
// Each wave owns TWO 16-row q-subtiles -> every K/V LDS fragment read feeds 2 MFMAs
// (per-CU ds_read count halves vs QB=128). 1 block/CU (96KB LDS), 256 blocks.
__global__ __launch_bounds__(512) void flash_attn4(
    const unsigned short* __restrict__ Qt, const unsigned short* __restrict__ Kt,
    const unsigned short* __restrict__ VpT, unsigned short* __restrict__ Oh) {
  const int bh = blockIdx.y;
  const int q0 = blockIdx.x * 256;
  const int tid = threadIdx.x, wave = tid >> 6, lane = tid & 63;
  const int r15 = lane & 15, g4 = lane >> 4;

  __shared__ unsigned short Ks[2][64 * 160];  // 40KB
  __shared__ unsigned short Vs[2][80 * 64];   // 20KB, V^T tile [d][kv] linear
  __shared__ unsigned short Ps[256 * 72];     // 36KB, wave-private 32-row slabs

  const unsigned short* Kbase = Kt + (size_t)bh * SS * DAUG;
  const unsigned short* Vbase = VpT + (size_t)bh * 80 * 1024;

  // hoist Q into registers: rows q0 + wave*32 + sub*16 + r15
  bf16x8 qf[2][5];
#pragma unroll
  for (int sub = 0; sub < 2; ++sub) {
    const unsigned short* Qg =
        Qt + ((size_t)bh * SS + q0 + wave * 32 + sub * 16 + r15) * DAUG;
#pragma unroll
    for (int kk = 0; kk < 5; ++kk) qf[sub][kk] = *(const bf16x8*)(Qg + kk * 32 + g4 * 8);
  }

  auto stageK = [&](int kv0, int buf) {
    const unsigned short* Kg = Kbase + (size_t)kv0 * DAUG;
#pragma unroll
    for (int j = 0; j < 2; ++j) {
      int ibase = j * 512 + wave * 64;
      int i = ibase + lane;
      int row = i / 20, c = i % 20;
      int cs = (c < 16) ? (c ^ (row & 7)) : (16 + ((c & 3) ^ (row & 3)));
      async16(Kg + (size_t)row * DAUG + cs * 8, &Ks[buf][0] + (size_t)ibase * 8);
    }
    if (wave < 4) {
      int ibase = 1024 + wave * 64;
      int i = ibase + lane;
      int row = i / 20, c = i % 20;
      int cs = (c < 16) ? (c ^ (row & 7)) : (16 + ((c & 3) ^ (row & 3)));
      async16(Kg + (size_t)row * DAUG + cs * 8, &Ks[buf][0] + (size_t)ibase * 8);
    }
  };
  auto stageV = [&](int kv0, int buf) {
    {
      int c = tid;
      int row = c >> 3, c8 = c & 7;
      async16(Vbase + (size_t)row * 1024 + kv0 + ((c8 ^ (row & 7)) << 3),
              &Vs[buf][0] + (size_t)c * 8);
    }
    if (tid < 128) {
      int c = 512 + tid;
      int row = c >> 3, c8 = c & 7;
      async16(Vbase + (size_t)row * 1024 + kv0 + ((c8 ^ (row & 7)) << 3),
              &Vs[buf][0] + (size_t)c * 8);
    }
  };

  stageK(0, 0);
  stageV(0, 0);
  __syncthreads();

  f32x4 accO[2][5];
#pragma unroll
  for (int sub = 0; sub < 2; ++sub)
#pragma unroll
    for (int df = 0; df < 5; ++df) accO[sub][df] = (f32x4){0.f, 0.f, 0.f, 0.f};
  float run_m[2][4] = {{-INFINITY, -INFINITY, -INFINITY, -INFINITY},
                       {-INFINITY, -INFINITY, -INFINITY, -INFINITY}};

  for (int t = 0; t < 16; ++t) {
    const int cur = t & 1, nxt = cur ^ 1;
    if (t < 15) {
      stageK((t + 1) * 64, nxt);
      stageV((t + 1) * 64, nxt);
    }

    // S = Q~ @ K~^T for 32 q-rows x 64 kv; each K fragment feeds both subtiles.
    f32x4 s[2][4];
#pragma unroll
    for (int sub = 0; sub < 2; ++sub)
#pragma unroll
      for (int f = 0; f < 4; ++f) s[sub][f] = (f32x4){0.f, 0.f, 0.f, 0.f};
    __builtin_amdgcn_s_setprio(1);
#pragma unroll
    for (int f = 0; f < 4; ++f) {
      int row = f * 16 + r15;
#pragma unroll
      for (int kk = 0; kk < 5; ++kk) {
        int c = kk * 4 + g4;
        int cs = (c < 16) ? (c ^ (row & 7)) : (16 + ((c & 3) ^ (row & 3)));
        bf16x8 kf = *(const bf16x8*)(&Ks[cur][(size_t)row * DAUG + cs * 8]);
        s[0][f] = __builtin_amdgcn_mfma_f32_16x16x32_bf16(qf[0][kk], kf, s[0][f], 0, 0, 0);
        s[1][f] = __builtin_amdgcn_mfma_f32_16x16x32_bf16(qf[1][kk], kf, s[1][f], 0, 0, 0);
      }
    }
    __builtin_amdgcn_s_setprio(0);

    // row max via DPP; T13 defer-rescale (THR=8, exp2 domain)
    float mx[2][4];
#pragma unroll
    for (int sub = 0; sub < 2; ++sub)
#pragma unroll
      for (int r = 0; r < 4; ++r)
        mx[sub][r] = rowmax16(
            fmaxf(fmaxf(s[sub][0][r], s[sub][1][r]), fmaxf(s[sub][2][r], s[sub][3][r])));

    bool stable = true;
#pragma unroll
    for (int sub = 0; sub < 2; ++sub)
#pragma unroll
      for (int r = 0; r < 4; ++r) stable = stable && (mx[sub][r] <= run_m[sub][r] + 8.f);
    if (!__all(stable)) {
#pragma unroll
      for (int sub = 0; sub < 2; ++sub)
#pragma unroll
        for (int r = 0; r < 4; ++r) {
          float mnew = fmaxf(run_m[sub][r], mx[sub][r]);
          float corr = exp2f(run_m[sub][r] - mnew);
          run_m[sub][r] = mnew;
#pragma unroll
          for (int df = 0; df < 5; ++df) accO[sub][df][r] *= corr;
        }
    }
#pragma unroll
    for (int sub = 0; sub < 2; ++sub)
#pragma unroll
      for (int r = 0; r < 4; ++r)
#pragma unroll
        for (int f = 0; f < 4; ++f) s[sub][f][r] = exp2f(s[sub][f][r] - run_m[sub][r]);

    // P to wave-private LDS slab (no barrier: same-wave write->read)
#pragma unroll
    for (int sub = 0; sub < 2; ++sub)
#pragma unroll
      for (int f = 0; f < 4; ++f)
#pragma unroll
        for (int r = 0; r < 4; ++r)
          ((__bf16*)Ps)[(wave * 32 + sub * 16 + g4 * 4 + r) * 72 + f * 16 + r15] =
              (__bf16)s[sub][f][r];

    // O += P @ V' : each V fragment feeds both subtiles
    __builtin_amdgcn_s_setprio(1);
#pragma unroll
    for (int ks = 0; ks < 2; ++ks) {
      bf16x8 pa0 = *(const bf16x8*)(Ps + (wave * 32 + r15) * 72 + ks * 32 + g4 * 8);
      bf16x8 pa1 = *(const bf16x8*)(Ps + (wave * 32 + 16 + r15) * 72 + ks * 32 + g4 * 8);
#pragma unroll
      for (int df = 0; df < 5; ++df) {
        int row = df * 16 + r15;
        bf16x8 vb =
            *(const bf16x8*)(&Vs[cur][(size_t)row * 64 + (((ks * 4 + g4) ^ (r15 & 7)) << 3)]);
        accO[0][df] = __builtin_amdgcn_mfma_f32_16x16x32_bf16(pa0, vb, accO[0][df], 0, 0, 0);
        accO[1][df] = __builtin_amdgcn_mfma_f32_16x16x32_bf16(pa1, vb, accO[1][df], 0, 0, 0);
      }
    }
    __builtin_amdgcn_s_setprio(0);

    __syncthreads();
  }

#pragma unroll
  for (int sub = 0; sub < 2; ++sub) {
    float rl[4];
#pragma unroll
    for (int r = 0; r < 4; ++r) {
      float l = __shfl(accO[sub][4][r], lane & 48, 64);  // sum at r15==0 of accO[sub][4]
      rl[r] = 1.f / l;
    }
#pragma unroll
    for (int df = 0; df < 4; ++df)
#pragma unroll
      for (int r = 0; r < 4; ++r) {
        float o = accO[sub][df][r] * rl[r];
        Oh[((size_t)bh * SS + q0 + wave * 32 + sub * 16 + g4 * 4 + r) * 64 + df * 16 + r15] =
            f2b(o);
      }
  }
}

extern "C" void kernel_launch(void* const* d_in, const int* in_sizes, int n_in,
                              void* d_out, int out_size, void* d_ws, size_t ws_size,
                              hipStream_t stream) {
  const float* query = (const float*)d_in[0];
  const float* key = (const float*)d_in[1];
  const float* value = (const float*)d_in[2];
  const float* pe = (const float*)d_in[3];
  const float* pp = (const float*)d_in[4];
  const float* cpe = (const float*)d_in[5];
  const float* cpp = (const float*)d_in[6];
  const float* relq = (const float*)d_in[7];
  const float* relk = (const float*)d_in[8];
  const float* relv = (const float*)d_in[9];
  const float* Wq = (const float*)d_in[10];
  const float* Wk = (const float*)d_in[11];
  const float* Wv = (const float*)d_in[12];
  const float* Wo = (const float*)d_in[13];
  float* out = (float*)d_out;
  char* ws = (char*)d_ws;

  unsigned short* Xq = (unsigned short*)(ws + 0);
  unsigned short* Xk = (unsigned short*)(ws + 8388608);
  unsigned short* Xv = (unsigned short*)(ws + 16777216);
  unsigned short* Wqb = (unsigned short*)(ws + 25165824);
  unsigned short* Wkb = (unsigned short*)(ws + 27262976);
  unsigned short* Wvb = (unsigned short*)(ws + 29360128);
  unsigned short* Wob = (unsigned short*)(ws + 31457280);
  unsigned short* Qt = (unsigned short*)(ws + 33554432);
  unsigned short* Kt = (unsigned short*)(ws + 54525952);
  unsigned short* Vp = (unsigned short*)(ws + 75497472);
  unsigned short* Oh = (unsigned short*)(ws + 0);         // alias Xq (dead after proj)
  unsigned short* VpT = (unsigned short*)(ws + 8388608);  // alias Xk+Xv (dead after proj)

  convert7<<<dim3(1024, 7, 1), 256, 0, stream>>>(query, key, value, Wq, Wk, Wv, Wo, Xq, Xk, Xv,
                                                 Wqb, Wkb, Wvb, Wob);
  proj_qkv<<<dim3(32, 8, 3), 256, 0, stream>>>(Xq, Xk, Xv, Wqb, Wkb, Wvb, Qt, Kt, Vp);
  aug_dots_mfma2<<<dim3(8, 64, 2), 256, 0, stream>>>(Qt, Kt, relk, relq);
  pos_copy2<<<dim3(16, 64, 2), 256, 0, stream>>>(Qt, Kt, cpe, cpp, pe, pp);
  vprime_T<<<dim3(16, 64, 1), 256, 0, stream>>>(Vp, pe, pp, relv, VpT);
  flash_attn4<<<dim3(4, 64, 1), 512, 0, stream>>>(Qt, Kt, VpT, Oh);
  gemm_out<<<dim3(32, 8, 1), 256, 0, stream>>>(Oh, Wob, out);
}

// Round 8
// 173.009 us; speedup vs baseline: 1.0444x; 1.0444x over previous
//
#include <hip/hip_runtime.h>
#include <hip/hip_bf16.h>
#include <stdint.h>

typedef float f32x4 __attribute__((ext_vector_type(4)));
typedef __bf16 bf16x8 __attribute__((ext_vector_type(8)));

#define NBH 64      // B*H
#define SS 1024     // SQ == SKV
#define DAUG 160    // augmented head dim 132 padded to 160
#define KAPPA 0.18033688011104293f  // 0.125 * log2(e), folded into Q~

static __device__ __forceinline__ unsigned short f2b(float f) {
  union { float f; uint32_t u; } v; v.f = f;
  return (unsigned short)((v.u + 0x7fffu + ((v.u >> 16) & 1u)) >> 16);
}
static __device__ __forceinline__ float b2f(unsigned short s) {
  union { uint32_t u; float f; } v; v.u = ((uint32_t)s) << 16;
  return v.f;
}

static __device__ __forceinline__ void async16(const void* g, void* l) {
  __builtin_amdgcn_global_load_lds(
      (const __attribute__((address_space(1))) uint32_t*)g,
      (__attribute__((address_space(3))) uint32_t*)l, 16, 0, 0);
}

// DPP max-reduce over 16-lane rows (VALU pipe, no LDS traffic).
template <int CTRL>
static __device__ __forceinline__ float dppmaxstep(float x) {
  int y = __builtin_amdgcn_update_dpp(__builtin_bit_cast(int, x), __builtin_bit_cast(int, x),
                                      CTRL, 0xF, 0xF, false);
  return fmaxf(x, __builtin_bit_cast(float, y));
}
static __device__ __forceinline__ float rowmax16(float x) {
  x = dppmaxstep<0x128>(x);  // row_ror:8
  x = dppmaxstep<0x124>(x);  // row_ror:4
  x = dppmaxstep<0x122>(x);  // row_ror:2
  x = dppmaxstep<0x121>(x);  // row_ror:1
  return x;
}

// ---------------- f32 -> bf16 conversion for 7 tensors ----------------
__global__ void convert7(const float* q, const float* k, const float* v,
                         const float* wq, const float* wk, const float* wv, const float* wo,
                         unsigned short* xq, unsigned short* xk, unsigned short* xv,
                         unsigned short* bwq, unsigned short* bwk, unsigned short* bwv,
                         unsigned short* bwo) {
  const float* s; unsigned short* d; int n;
  switch (blockIdx.y) {
    case 0: s = q;  d = xq;  n = 4194304; break;
    case 1: s = k;  d = xk;  n = 4194304; break;
    case 2: s = v;  d = xv;  n = 4194304; break;
    case 3: s = wq; d = bwq; n = 1048576; break;
    case 4: s = wk; d = bwk; n = 1048576; break;
    case 5: s = wv; d = bwv; n = 1048576; break;
    default: s = wo; d = bwo; n = 1048576; break;
  }
  int n4 = n >> 2;
  for (int i = blockIdx.x * blockDim.x + threadIdx.x; i < n4; i += gridDim.x * blockDim.x) {
    float4 f = ((const float4*)s)[i];
    ushort4 o;
    o.x = f2b(f.x); o.y = f2b(f.y); o.z = f2b(f.z); o.w = f2b(f.w);
    ((ushort4*)d)[i] = o;
  }
}

// ---------------- QKV projection GEMM + fused rank-34 augmentation ----------------
// grid (32,8,3) with T1 XCD swizzle. BM=BN=128, BK=32, 4 waves.
// z=0: Qt (KAPPA), epilogue-aug relk -> cols 64..97
// z=1: Kt,          epilogue-aug relq -> cols 98..131
// z=2: Vp, plain epilogue.
__global__ __launch_bounds__(256) void proj_qkv(
    const unsigned short* __restrict__ Xq, const unsigned short* __restrict__ Xk,
    const unsigned short* __restrict__ Xv, const unsigned short* __restrict__ Wqb,
    const unsigned short* __restrict__ Wkb, const unsigned short* __restrict__ Wvb,
    unsigned short* __restrict__ Qt, unsigned short* __restrict__ Kt,
    unsigned short* __restrict__ Vp, const float* __restrict__ relk,
    const float* __restrict__ relq) {
  const int n_ = blockIdx.x + 32 * (blockIdx.y + 8 * blockIdx.z);
  const int o_ = (n_ & 7) * 96 + (n_ >> 3);
  const int bx = o_ & 31, by = (o_ >> 5) & 7, z = o_ >> 8;

  const unsigned short* A = (z == 0) ? Xq : (z == 1) ? Xk : Xv;
  const unsigned short* Bw = (z == 0) ? Wqb : (z == 1) ? Wkb : Wvb;
  unsigned short* Dst = (z == 0) ? Qt : (z == 1) ? Kt : Vp;
  const int dstride = (z == 2) ? 64 : DAUG;
  const float sc = (z == 0) ? KAPPA : 1.0f;

  // SMEM layout: [0..8191] At dbuf, [8192..16383] Bt dbuf (ushort idx);
  // after K-loop: Ys = SMEM[0..16383] (128x128 bf16, XOR-swizzled);
  // RelL = SMEM[16384..23295] (2 heads x 48 x 72).
  __shared__ unsigned short SMEM[23296];
  unsigned short* AtB = SMEM;
  unsigned short* BtB = SMEM + 8192;
  unsigned short* RelL = SMEM + 16384;
  unsigned short* Ys = SMEM;

  const int tid = threadIdx.x, wave = tid >> 6, lane = tid & 63;
  const int r15 = lane & 15, g4 = lane >> 4;
  const int i0 = bx * 128, j0 = by * 128;
  const int wm = (wave >> 1) * 64, wn = (wave & 1) * 64;

  // stage rel (2 heads) into LDS, bf16, rows padded 34->48
  if (z < 2) {
    const float* rel = (z == 0) ? relk : relq;
    const int h0 = by * 2;
    for (int idx = tid; idx < 2 * 48 * 64; idx += 256) {
      int hh = idx / (48 * 64), rem = idx % (48 * 64);
      int r = rem >> 6, d = rem & 63;
      float v = (r < 34) ? rel[(((size_t)(h0 + hh)) * 34 + r) * 64 + d] : 0.f;
      RelL[(hh * 48 + r) * 72 + d] = f2b(v);
    }
  }

  auto stage = [&](int k0, int buf) {
#pragma unroll
    for (int c = 0; c < 2; ++c) {
      int ch = (wave * 2 + c) * 64 + lane;
      int row = ch >> 2, cg = ch & 3;
      async16(A + (size_t)(i0 + row) * 1024 + k0 + cg * 8, AtB + buf * 4096 + (wave * 2 + c) * 512);
      async16(Bw + (size_t)(j0 + row) * 1024 + k0 + cg * 8, BtB + buf * 4096 + (wave * 2 + c) * 512);
    }
  };

  f32x4 acc[4][4];
#pragma unroll
  for (int m = 0; m < 4; ++m)
#pragma unroll
    for (int n = 0; n < 4; ++n) acc[m][n] = (f32x4){0.f, 0.f, 0.f, 0.f};

  stage(0, 0);
  __syncthreads();

  for (int it = 0; it < 32; ++it) {
    const int cur = it & 1, nxt = cur ^ 1;
    if (it < 31) stage((it + 1) * 32, nxt);
    bf16x8 af[4], bf[4];
#pragma unroll
    for (int m = 0; m < 4; ++m)
      af[m] = *(const bf16x8*)(AtB + cur * 4096 + (wm + m * 16 + r15) * 32 + g4 * 8);
#pragma unroll
    for (int n = 0; n < 4; ++n)
      bf[n] = *(const bf16x8*)(BtB + cur * 4096 + (wn + n * 16 + r15) * 32 + g4 * 8);
    __builtin_amdgcn_s_setprio(1);
#pragma unroll
    for (int m = 0; m < 4; ++m)
#pragma unroll
      for (int n = 0; n < 4; ++n)
        acc[m][n] = __builtin_amdgcn_mfma_f32_16x16x32_bf16(af[m], bf[n], acc[m][n], 0, 0, 0);
    __builtin_amdgcn_s_setprio(0);
    __syncthreads();
  }

  // main epilogue: write d-columns to global; z<2 also deposits Y-tile in LDS.
#pragma unroll
  for (int m = 0; m < 4; ++m)
#pragma unroll
    for (int n = 0; n < 4; ++n)
#pragma unroll
      for (int r = 0; r < 4; ++r) {
        int lrow = wm + m * 16 + g4 * 4 + r;
        int lcol = wn + n * 16 + r15;
        int i = i0 + lrow, j = j0 + lcol;
        float y = acc[m][n][r] * sc;
        int b = i >> 10, s = i & 1023, h = j >> 6, d = j & 63;
        Dst[(((size_t)b * 16 + h) * SS + s) * dstride + d] = f2b(y);
        if (z < 2) {
          int c8 = (lcol >> 3) ^ (lrow & 7);
          Ys[lrow * 128 + c8 * 8 + (lcol & 7)] = f2b(y);
        }
      }

  if (z < 2) {
    const int cbase = (z == 0) ? 64 : 98;
    __syncthreads();
#pragma unroll
    for (int hh = 0; hh < 2; ++hh) {
      bf16x8 bfr[3][2];
#pragma unroll
      for (int n = 0; n < 3; ++n)
#pragma unroll
        for (int st = 0; st < 2; ++st)
          bfr[n][st] = *(const bf16x8*)(RelL + (hh * 48 + n * 16 + r15) * 72 + st * 32 + g4 * 8);

      f32x4 a2[2][3];
#pragma unroll
      for (int m2 = 0; m2 < 2; ++m2)
#pragma unroll
        for (int n = 0; n < 3; ++n) a2[m2][n] = (f32x4){0.f, 0.f, 0.f, 0.f};

#pragma unroll
      for (int m2 = 0; m2 < 2; ++m2) {
        int lrow = wave * 32 + m2 * 16 + r15;
        int c8a = (hh * 8 + 0 * 4 + g4) ^ (lrow & 7);
        int c8b = (hh * 8 + 1 * 4 + g4) ^ (lrow & 7);
        bf16x8 a0 = *(const bf16x8*)(Ys + lrow * 128 + c8a * 8);
        bf16x8 a1 = *(const bf16x8*)(Ys + lrow * 128 + c8b * 8);
#pragma unroll
        for (int n = 0; n < 3; ++n) {
          a2[m2][n] = __builtin_amdgcn_mfma_f32_16x16x32_bf16(a0, bfr[n][0], a2[m2][n], 0, 0, 0);
          a2[m2][n] = __builtin_amdgcn_mfma_f32_16x16x32_bf16(a1, bfr[n][1], a2[m2][n], 0, 0, 0);
        }
      }

      const int h = by * 2 + hh;
#pragma unroll
      for (int m2 = 0; m2 < 2; ++m2)
#pragma unroll
        for (int n = 0; n < 3; ++n) {
          int col = n * 16 + r15;
          if (col < 34) {
#pragma unroll
            for (int rr = 0; rr < 4; ++rr) {
              int i = i0 + wave * 32 + m2 * 16 + g4 * 4 + rr;
              int b = i >> 10, s = i & 1023;
              Dst[(((size_t)b * 16 + h) * SS + s) * DAUG + cbase + col] = f2b(a2[m2][n][rr]);
            }
          }
        }
    }
  }
}

// ---------------- output projection GEMM: out = Oh @ Wo^T, 2-phase dbuf, XCD swizzle -----
__global__ __launch_bounds__(256) void gemm_out(const unsigned short* __restrict__ Oh,
                                                const unsigned short* __restrict__ Wob,
                                                float* __restrict__ Out) {
  const int n_ = blockIdx.x + 32 * blockIdx.y;
  const int o_ = (n_ & 7) * 32 + (n_ >> 3);
  const int bx = o_ & 31, by = o_ >> 5;

  __shared__ unsigned short At[2][128 * 32];
  __shared__ unsigned short Bt[2][128 * 32];

  const int tid = threadIdx.x, wave = tid >> 6, lane = tid & 63;
  const int r15 = lane & 15, g4 = lane >> 4;
  const int i0 = bx * 128, j0 = by * 128;
  const int wm = (wave >> 1) * 64, wn = (wave & 1) * 64;

  auto stage = [&](int k0, int buf) {
#pragma unroll
    for (int c = 0; c < 2; ++c) {
      int ch = (wave * 2 + c) * 64 + lane;
      int row = ch >> 2, cg = ch & 3;
      int i = i0 + row, b = i >> 10, s = i & 1023;
      int kcol = k0 + cg * 8, h = kcol >> 6, dd = kcol & 63;
      async16(Oh + (((size_t)b * 16 + h) * SS + s) * 64 + dd, &At[buf][0] + (wave * 2 + c) * 512);
      async16(Wob + (size_t)(j0 + row) * 1024 + k0 + cg * 8, &Bt[buf][0] + (wave * 2 + c) * 512);
    }
  };

  f32x4 acc[4][4];
#pragma unroll
  for (int m = 0; m < 4; ++m)
#pragma unroll
    for (int n = 0; n < 4; ++n) acc[m][n] = (f32x4){0.f, 0.f, 0.f, 0.f};

  stage(0, 0);
  __syncthreads();

  for (int it = 0; it < 32; ++it) {
    const int cur = it & 1, nxt = cur ^ 1;
    if (it < 31) stage((it + 1) * 32, nxt);
    bf16x8 af[4], bf[4];
#pragma unroll
    for (int m = 0; m < 4; ++m)
      af[m] = *(const bf16x8*)(&At[cur][(wm + m * 16 + r15) * 32 + g4 * 8]);
#pragma unroll
    for (int n = 0; n < 4; ++n)
      bf[n] = *(const bf16x8*)(&Bt[cur][(wn + n * 16 + r15) * 32 + g4 * 8]);
    __builtin_amdgcn_s_setprio(1);
#pragma unroll
    for (int m = 0; m < 4; ++m)
#pragma unroll
      for (int n = 0; n < 4; ++n)
        acc[m][n] = __builtin_amdgcn_mfma_f32_16x16x32_bf16(af[m], bf[n], acc[m][n], 0, 0, 0);
    __builtin_amdgcn_s_setprio(0);
    __syncthreads();
  }

#pragma unroll
  for (int m = 0; m < 4; ++m)
#pragma unroll
    for (int n = 0; n < 4; ++n)
#pragma unroll
      for (int r = 0; r < 4; ++r) {
        int i = i0 + wm + m * 16 + g4 * 4 + r;
        int j = j0 + wn + n * 16 + r15;
        Out[(size_t)i * 1024 + j] = acc[m][n][r];
      }
}

// ---------------- merged pos transpose-copy + zero pad + V' build ----------------
// z=0: Qt cols 98..131 = KAPPA*[cpe;cpp]^T, pad; z=1: Kt cols 64..97 = [pe;pp]^T, pad,
// plus VpT build (rows 0..63 data, row 64 ones, rows 65..79 zero).
__global__ __launch_bounds__(256) void pos_vp(unsigned short* __restrict__ Qt,
                                              unsigned short* __restrict__ Kt,
                                              const float* __restrict__ cpe,
                                              const float* __restrict__ cpp,
                                              const float* __restrict__ pe,
                                              const float* __restrict__ pp,
                                              const unsigned short* __restrict__ Vp,
                                              const float* __restrict__ relv,
                                              unsigned short* __restrict__ VpT) {
  const int z = blockIdx.z;
  unsigned short* T = z ? Kt : Qt;
  const float* Pe = z ? pe : cpe;
  const float* Pp = z ? pp : cpp;
  const int cbase = z ? 64 : 98;
  const float scale = z ? 1.0f : KAPPA;
  const int bh = blockIdx.y, h = bh & 15, s0 = blockIdx.x * 64;
  const int tid = threadIdx.x;
  __shared__ float PeL[17][65];
  __shared__ float PpL[17][65];
  __shared__ unsigned short VT[64][72];

  for (int idx = tid; idx < 17 * 64; idx += 256) {
    int r = idx >> 6, c = idx & 63;
    PeL[r][c] = Pe[((size_t)bh * 17 + r) * SS + s0 + c];
    PpL[r][c] = Pp[((size_t)bh * 17 + r) * SS + s0 + c];
  }
  __syncthreads();

  for (int idx = tid; idx < 4096; idx += 256) {
    int s = idx >> 6, j = idx & 63;
    if (j < 34) {
      float v = (j < 17) ? PeL[j][s] : PpL[j - 17][s];
      T[((size_t)bh * SS + s0 + s) * DAUG + cbase + j] = f2b(v * scale);
    } else if (j < 62) {
      T[((size_t)bh * SS + s0 + s) * DAUG + 132 + (j - 34)] = 0;
    }
  }

  if (z == 1) {
    const int d = tid & 63, sg = tid >> 6;
    float acc[16];
#pragma unroll
    for (int si = 0; si < 16; ++si) acc[si] = 0.f;
    for (int r = 0; r < 17; ++r) {
      float ve = relv[((size_t)h * 34 + r) * 64 + d];
      float vpv = relv[((size_t)h * 34 + 17 + r) * 64 + d];
#pragma unroll
      for (int si = 0; si < 16; ++si) {
        int s = sg * 16 + si;
        acc[si] += PeL[r][s] * ve + PpL[r][s] * vpv;
      }
    }
#pragma unroll
    for (int si = 0; si < 16; ++si) {
      int s = sg * 16 + si;
      float v = b2f(Vp[((size_t)bh * SS + s0 + s) * 64 + d]) + acc[si];
      VT[d][s] = f2b(v);
    }
    __syncthreads();

    for (int c = tid; c < 512; c += 256) {
      int row = c >> 3, c8 = c & 7;
      uint4 v = *(const uint4*)&VT[row][c8 * 8];
      *(uint4*)(VpT + ((size_t)bh * 80 + row) * 1024 + s0 + c8 * 8) = v;
    }
    if (tid < 128) {
      int row = 64 + (tid >> 3), c8 = tid & 7;
      uint32_t w = (row == 64) ? 0x3F803F80u : 0u;
      uint4 v = {w, w, w, w};
      *(uint4*)(VpT + ((size_t)bh * 80 + row) * 1024 + s0 + c8 * 8) = v;
    }
  }
}

// ---------------- flash attention v5 (reverted from v6): QB=128, 2 blocks/CU ----------
__global__ __launch_bounds__(512, 4) void flash_attn3(
    const unsigned short* __restrict__ Qt, const unsigned short* __restrict__ Kt,
    const unsigned short* __restrict__ VpT, unsigned short* __restrict__ Oh) {
  const int bh = blockIdx.y;
  const int q0 = blockIdx.x * 128;
  const int tid = threadIdx.x, wave = tid >> 6, lane = tid & 63;
  const int r15 = lane & 15, g4 = lane >> 4;

  __shared__ unsigned short Ks[2][64 * 160];
  __shared__ unsigned short Vs[2][80 * 64];  // V^T tile: [d 0..79][kv 0..63], linear
  __shared__ unsigned short Ps[128 * 72];

  const unsigned short* Kbase = Kt + (size_t)bh * SS * DAUG;
  const unsigned short* Vbase = VpT + (size_t)bh * 80 * 1024;

  bf16x8 qf[5];
  {
    const unsigned short* Qg = Qt + ((size_t)bh * SS + q0 + wave * 16 + r15) * DAUG;
#pragma unroll
    for (int kk = 0; kk < 5; ++kk) qf[kk] = *(const bf16x8*)(Qg + kk * 32 + g4 * 8);
  }

  auto stageK = [&](int kv0, int buf) {
    const unsigned short* Kg = Kbase + (size_t)kv0 * DAUG;
#pragma unroll
    for (int j = 0; j < 2; ++j) {
      int ibase = j * 512 + wave * 64;
      int i = ibase + lane;
      int row = i / 20, c = i % 20;
      int cs = (c < 16) ? (c ^ (row & 7)) : (16 + ((c & 3) ^ (row & 3)));
      async16(Kg + (size_t)row * DAUG + cs * 8, &Ks[buf][0] + (size_t)ibase * 8);
    }
    if (wave < 4) {
      int ibase = 1024 + wave * 64;
      int i = ibase + lane;
      int row = i / 20, c = i % 20;
      int cs = (c < 16) ? (c ^ (row & 7)) : (16 + ((c & 3) ^ (row & 3)));
      async16(Kg + (size_t)row * DAUG + cs * 8, &Ks[buf][0] + (size_t)ibase * 8);
    }
  };
  auto stageV = [&](int kv0, int buf) {
    {
      int c = tid;
      int row = c >> 3, c8 = c & 7;
      async16(Vbase + (size_t)row * 1024 + kv0 + ((c8 ^ (row & 7)) << 3),
              &Vs[buf][0] + (size_t)c * 8);
    }
    if (tid < 128) {
      int c = 512 + tid;
      int row = c >> 3, c8 = c & 7;
      async16(Vbase + (size_t)row * 1024 + kv0 + ((c8 ^ (row & 7)) << 3),
              &Vs[buf][0] + (size_t)c * 8);
    }
  };

  stageK(0, 0);
  stageV(0, 0);
  __syncthreads();

  f32x4 accO[5];
#pragma unroll
  for (int df = 0; df < 5; ++df) accO[df] = (f32x4){0.f, 0.f, 0.f, 0.f};
  float run_m[4] = {-INFINITY, -INFINITY, -INFINITY, -INFINITY};

  for (int t = 0; t < 16; ++t) {
    const int cur = t & 1, nxt = cur ^ 1;
    if (t < 15) {
      stageK((t + 1) * 64, nxt);
      stageV((t + 1) * 64, nxt);
    }

    f32x4 s[4];
#pragma unroll
    for (int f = 0; f < 4; ++f) s[f] = (f32x4){0.f, 0.f, 0.f, 0.f};
    __builtin_amdgcn_s_setprio(1);
#pragma unroll
    for (int f = 0; f < 4; ++f) {
      int row = f * 16 + r15;
#pragma unroll
      for (int kk = 0; kk < 5; ++kk) {
        int c = kk * 4 + g4;
        int cs = (c < 16) ? (c ^ (row & 7)) : (16 + ((c & 3) ^ (row & 3)));
        bf16x8 kf = *(const bf16x8*)(&Ks[cur][(size_t)row * DAUG + cs * 8]);
        s[f] = __builtin_amdgcn_mfma_f32_16x16x32_bf16(qf[kk], kf, s[f], 0, 0, 0);
      }
    }
    __builtin_amdgcn_s_setprio(0);

    float mx[4];
#pragma unroll
    for (int r = 0; r < 4; ++r)
      mx[r] = rowmax16(fmaxf(fmaxf(s[0][r], s[1][r]), fmaxf(s[2][r], s[3][r])));

    bool stable = (mx[0] <= run_m[0] + 8.f) && (mx[1] <= run_m[1] + 8.f) &&
                  (mx[2] <= run_m[2] + 8.f) && (mx[3] <= run_m[3] + 8.f);
    if (!__all(stable)) {
#pragma unroll
      for (int r = 0; r < 4; ++r) {
        float mnew = fmaxf(run_m[r], mx[r]);
        float corr = exp2f(run_m[r] - mnew);
        run_m[r] = mnew;
#pragma unroll
        for (int df = 0; df < 5; ++df) accO[df][r] *= corr;
      }
    }
#pragma unroll
    for (int r = 0; r < 4; ++r)
#pragma unroll
      for (int f = 0; f < 4; ++f) s[f][r] = exp2f(s[f][r] - run_m[r]);

#pragma unroll
    for (int f = 0; f < 4; ++f)
#pragma unroll
      for (int r = 0; r < 4; ++r)
        ((__bf16*)Ps)[(wave * 16 + g4 * 4 + r) * 72 + f * 16 + r15] = (__bf16)s[f][r];

    __builtin_amdgcn_s_setprio(1);
#pragma unroll
    for (int ks = 0; ks < 2; ++ks) {
      bf16x8 pa = *(const bf16x8*)(Ps + (wave * 16 + r15) * 72 + ks * 32 + g4 * 8);
#pragma unroll
      for (int df = 0; df < 5; ++df) {
        int row = df * 16 + r15;
        bf16x8 vb = *(const bf16x8*)(&Vs[cur][(size_t)row * 64 + (((ks * 4 + g4) ^ (r15 & 7)) << 3)]);
        accO[df] = __builtin_amdgcn_mfma_f32_16x16x32_bf16(pa, vb, accO[df], 0, 0, 0);
      }
    }
    __builtin_amdgcn_s_setprio(0);

    __syncthreads();
  }

  float rl[4];
#pragma unroll
  for (int r = 0; r < 4; ++r) {
    float l = __shfl(accO[4][r], lane & 48, 64);  // sum lives at r15==0 of accO[4]
    rl[r] = 1.f / l;
  }
#pragma unroll
  for (int df = 0; df < 4; ++df)
#pragma unroll
    for (int r = 0; r < 4; ++r) {
      float o = accO[df][r] * rl[r];
      Oh[((size_t)bh * SS + q0 + wave * 16 + g4 * 4 + r) * 64 + df * 16 + r15] = f2b(o);
    }
}

extern "C" void kernel_launch(void* const* d_in, const int* in_sizes, int n_in,
                              void* d_out, int out_size, void* d_ws, size_t ws_size,
                              hipStream_t stream) {
  const float* query = (const float*)d_in[0];
  const float* key = (const float*)d_in[1];
  const float* value = (const float*)d_in[2];
  const float* pe = (const float*)d_in[3];
  const float* pp = (const float*)d_in[4];
  const float* cpe = (const float*)d_in[5];
  const float* cpp = (const float*)d_in[6];
  const float* relq = (const float*)d_in[7];
  const float* relk = (const float*)d_in[8];
  const float* relv = (const float*)d_in[9];
  const float* Wq = (const float*)d_in[10];
  const float* Wk = (const float*)d_in[11];
  const float* Wv = (const float*)d_in[12];
  const float* Wo = (const float*)d_in[13];
  float* out = (float*)d_out;
  char* ws = (char*)d_ws;

  unsigned short* Xq = (unsigned short*)(ws + 0);
  unsigned short* Xk = (unsigned short*)(ws + 8388608);
  unsigned short* Xv = (unsigned short*)(ws + 16777216);
  unsigned short* Wqb = (unsigned short*)(ws + 25165824);
  unsigned short* Wkb = (unsigned short*)(ws + 27262976);
  unsigned short* Wvb = (unsigned short*)(ws + 29360128);
  unsigned short* Wob = (unsigned short*)(ws + 31457280);
  unsigned short* Qt = (unsigned short*)(ws + 33554432);
  unsigned short* Kt = (unsigned short*)(ws + 54525952);
  unsigned short* Vp = (unsigned short*)(ws + 75497472);
  unsigned short* Oh = (unsigned short*)(ws + 0);         // alias Xq (dead after proj)
  unsigned short* VpT = (unsigned short*)(ws + 8388608);  // alias Xk+Xv (dead after proj)

  convert7<<<dim3(1024, 7, 1), 256, 0, stream>>>(query, key, value, Wq, Wk, Wv, Wo, Xq, Xk, Xv,
                                                 Wqb, Wkb, Wvb, Wob);
  proj_qkv<<<dim3(32, 8, 3), 256, 0, stream>>>(Xq, Xk, Xv, Wqb, Wkb, Wvb, Qt, Kt, Vp, relk, relq);
  pos_vp<<<dim3(16, 64, 2), 256, 0, stream>>>(Qt, Kt, cpe, cpp, pe, pp, Vp, relv, VpT);
  flash_attn3<<<dim3(8, 64, 1), 512, 0, stream>>>(Qt, Kt, VpT, Oh);
  gemm_out<<<dim3(32, 8, 1), 256, 0, stream>>>(Oh, Wob, out);
}

// Round 9
// 168.256 us; speedup vs baseline: 1.0739x; 1.0282x over previous
//
#include <hip/hip_runtime.h>
#include <hip/hip_bf16.h>
#include <stdint.h>

typedef float f32x4 __attribute__((ext_vector_type(4)));
typedef float f32x16 __attribute__((ext_vector_type(16)));
typedef __bf16 bf16x8 __attribute__((ext_vector_type(8)));

#define NBH 64      // B*H
#define SS 1024     // SQ == SKV
#define DAUG 160    // augmented head dim 132 padded to 160
#define KAPPA 0.18033688011104293f  // 0.125 * log2(e), folded into Q~

static __device__ __forceinline__ unsigned short f2b(float f) {
  union { float f; uint32_t u; } v; v.f = f;
  return (unsigned short)((v.u + 0x7fffu + ((v.u >> 16) & 1u)) >> 16);
}
static __device__ __forceinline__ float b2f(unsigned short s) {
  union { uint32_t u; float f; } v; v.u = ((uint32_t)s) << 16;
  return v.f;
}
static __device__ __forceinline__ uint32_t pk2(float a, float b) {
  return (uint32_t)f2b(a) | ((uint32_t)f2b(b) << 16);
}

static __device__ __forceinline__ void async16(const void* g, void* l) {
  __builtin_amdgcn_global_load_lds(
      (const __attribute__((address_space(1))) uint32_t*)g,
      (__attribute__((address_space(3))) uint32_t*)l, 16, 0, 0);
}

// K-tile chunk swizzle (20 16B-chunks per 160-elem row)
static __device__ __forceinline__ int ksw(int c, int row) {
  return (c < 16) ? (c ^ (row & 7)) : (16 + ((c & 3) ^ (row & 3)));
}

// ---------------- f32 -> bf16 conversion for 7 tensors ----------------
__global__ void convert7(const float* q, const float* k, const float* v,
                         const float* wq, const float* wk, const float* wv, const float* wo,
                         unsigned short* xq, unsigned short* xk, unsigned short* xv,
                         unsigned short* bwq, unsigned short* bwk, unsigned short* bwv,
                         unsigned short* bwo) {
  const float* s; unsigned short* d; int n;
  switch (blockIdx.y) {
    case 0: s = q;  d = xq;  n = 4194304; break;
    case 1: s = k;  d = xk;  n = 4194304; break;
    case 2: s = v;  d = xv;  n = 4194304; break;
    case 3: s = wq; d = bwq; n = 1048576; break;
    case 4: s = wk; d = bwk; n = 1048576; break;
    case 5: s = wv; d = bwv; n = 1048576; break;
    default: s = wo; d = bwo; n = 1048576; break;
  }
  int n4 = n >> 2;
  for (int i = blockIdx.x * blockDim.x + threadIdx.x; i < n4; i += gridDim.x * blockDim.x) {
    float4 f = ((const float4*)s)[i];
    ushort4 o;
    o.x = f2b(f.x); o.y = f2b(f.y); o.z = f2b(f.z); o.w = f2b(f.w);
    ((ushort4*)d)[i] = o;
  }
}

// ---------------- QKV projection GEMM + fused rank-34 augmentation ----------------
__global__ __launch_bounds__(256) void proj_qkv(
    const unsigned short* __restrict__ Xq, const unsigned short* __restrict__ Xk,
    const unsigned short* __restrict__ Xv, const unsigned short* __restrict__ Wqb,
    const unsigned short* __restrict__ Wkb, const unsigned short* __restrict__ Wvb,
    unsigned short* __restrict__ Qt, unsigned short* __restrict__ Kt,
    unsigned short* __restrict__ Vp, const float* __restrict__ relk,
    const float* __restrict__ relq) {
  const int n_ = blockIdx.x + 32 * (blockIdx.y + 8 * blockIdx.z);
  const int o_ = (n_ & 7) * 96 + (n_ >> 3);
  const int bx = o_ & 31, by = (o_ >> 5) & 7, z = o_ >> 8;

  const unsigned short* A = (z == 0) ? Xq : (z == 1) ? Xk : Xv;
  const unsigned short* Bw = (z == 0) ? Wqb : (z == 1) ? Wkb : Wvb;
  unsigned short* Dst = (z == 0) ? Qt : (z == 1) ? Kt : Vp;
  const int dstride = (z == 2) ? 64 : DAUG;
  const float sc = (z == 0) ? KAPPA : 1.0f;

  __shared__ unsigned short SMEM[23296];
  unsigned short* AtB = SMEM;
  unsigned short* BtB = SMEM + 8192;
  unsigned short* RelL = SMEM + 16384;
  unsigned short* Ys = SMEM;

  const int tid = threadIdx.x, wave = tid >> 6, lane = tid & 63;
  const int r15 = lane & 15, g4 = lane >> 4;
  const int i0 = bx * 128, j0 = by * 128;
  const int wm = (wave >> 1) * 64, wn = (wave & 1) * 64;

  if (z < 2) {
    const float* rel = (z == 0) ? relk : relq;
    const int h0 = by * 2;
    for (int idx = tid; idx < 2 * 48 * 64; idx += 256) {
      int hh = idx / (48 * 64), rem = idx % (48 * 64);
      int r = rem >> 6, d = rem & 63;
      float v = (r < 34) ? rel[(((size_t)(h0 + hh)) * 34 + r) * 64 + d] : 0.f;
      RelL[(hh * 48 + r) * 72 + d] = f2b(v);
    }
  }

  auto stage = [&](int k0, int buf) {
#pragma unroll
    for (int c = 0; c < 2; ++c) {
      int ch = (wave * 2 + c) * 64 + lane;
      int row = ch >> 2, cg = ch & 3;
      async16(A + (size_t)(i0 + row) * 1024 + k0 + cg * 8, AtB + buf * 4096 + (wave * 2 + c) * 512);
      async16(Bw + (size_t)(j0 + row) * 1024 + k0 + cg * 8, BtB + buf * 4096 + (wave * 2 + c) * 512);
    }
  };

  f32x4 acc[4][4];
#pragma unroll
  for (int m = 0; m < 4; ++m)
#pragma unroll
    for (int n = 0; n < 4; ++n) acc[m][n] = (f32x4){0.f, 0.f, 0.f, 0.f};

  stage(0, 0);
  __syncthreads();

  for (int it = 0; it < 32; ++it) {
    const int cur = it & 1, nxt = cur ^ 1;
    if (it < 31) stage((it + 1) * 32, nxt);
    bf16x8 af[4], bf[4];
#pragma unroll
    for (int m = 0; m < 4; ++m)
      af[m] = *(const bf16x8*)(AtB + cur * 4096 + (wm + m * 16 + r15) * 32 + g4 * 8);
#pragma unroll
    for (int n = 0; n < 4; ++n)
      bf[n] = *(const bf16x8*)(BtB + cur * 4096 + (wn + n * 16 + r15) * 32 + g4 * 8);
    __builtin_amdgcn_s_setprio(1);
#pragma unroll
    for (int m = 0; m < 4; ++m)
#pragma unroll
      for (int n = 0; n < 4; ++n)
        acc[m][n] = __builtin_amdgcn_mfma_f32_16x16x32_bf16(af[m], bf[n], acc[m][n], 0, 0, 0);
    __builtin_amdgcn_s_setprio(0);
    __syncthreads();
  }

#pragma unroll
  for (int m = 0; m < 4; ++m)
#pragma unroll
    for (int n = 0; n < 4; ++n)
#pragma unroll
      for (int r = 0; r < 4; ++r) {
        int lrow = wm + m * 16 + g4 * 4 + r;
        int lcol = wn + n * 16 + r15;
        int i = i0 + lrow, j = j0 + lcol;
        float y = acc[m][n][r] * sc;
        int b = i >> 10, s = i & 1023, h = j >> 6, d = j & 63;
        Dst[(((size_t)b * 16 + h) * SS + s) * dstride + d] = f2b(y);
        if (z < 2) {
          int c8 = (lcol >> 3) ^ (lrow & 7);
          Ys[lrow * 128 + c8 * 8 + (lcol & 7)] = f2b(y);
        }
      }

  if (z < 2) {
    const int cbase = (z == 0) ? 64 : 98;
    __syncthreads();
#pragma unroll
    for (int hh = 0; hh < 2; ++hh) {
      bf16x8 bfr[3][2];
#pragma unroll
      for (int n = 0; n < 3; ++n)
#pragma unroll
        for (int st = 0; st < 2; ++st)
          bfr[n][st] = *(const bf16x8*)(RelL + (hh * 48 + n * 16 + r15) * 72 + st * 32 + g4 * 8);

      f32x4 a2[2][3];
#pragma unroll
      for (int m2 = 0; m2 < 2; ++m2)
#pragma unroll
        for (int n = 0; n < 3; ++n) a2[m2][n] = (f32x4){0.f, 0.f, 0.f, 0.f};

#pragma unroll
      for (int m2 = 0; m2 < 2; ++m2) {
        int lrow = wave * 32 + m2 * 16 + r15;
        int c8a = (hh * 8 + 0 * 4 + g4) ^ (lrow & 7);
        int c8b = (hh * 8 + 1 * 4 + g4) ^ (lrow & 7);
        bf16x8 a0 = *(const bf16x8*)(Ys + lrow * 128 + c8a * 8);
        bf16x8 a1 = *(const bf16x8*)(Ys + lrow * 128 + c8b * 8);
#pragma unroll
        for (int n = 0; n < 3; ++n) {
          a2[m2][n] = __builtin_amdgcn_mfma_f32_16x16x32_bf16(a0, bfr[n][0], a2[m2][n], 0, 0, 0);
          a2[m2][n] = __builtin_amdgcn_mfma_f32_16x16x32_bf16(a1, bfr[n][1], a2[m2][n], 0, 0, 0);
        }
      }

      const int h = by * 2 + hh;
#pragma unroll
      for (int m2 = 0; m2 < 2; ++m2)
#pragma unroll
        for (int n = 0; n < 3; ++n) {
          int col = n * 16 + r15;
          if (col < 34) {
#pragma unroll
            for (int rr = 0; rr < 4; ++rr) {
              int i = i0 + wave * 32 + m2 * 16 + g4 * 4 + rr;
              int b = i >> 10, s = i & 1023;
              Dst[(((size_t)b * 16 + h) * SS + s) * DAUG + cbase + col] = f2b(a2[m2][n][rr]);
            }
          }
        }
    }
  }
}

// ---------------- output projection GEMM ----------------
__global__ __launch_bounds__(256) void gemm_out(const unsigned short* __restrict__ Oh,
                                                const unsigned short* __restrict__ Wob,
                                                float* __restrict__ Out) {
  const int n_ = blockIdx.x + 32 * blockIdx.y;
  const int o_ = (n_ & 7) * 32 + (n_ >> 3);
  const int bx = o_ & 31, by = o_ >> 5;

  __shared__ unsigned short At[2][128 * 32];
  __shared__ unsigned short Bt[2][128 * 32];

  const int tid = threadIdx.x, wave = tid >> 6, lane = tid & 63;
  const int r15 = lane & 15, g4 = lane >> 4;
  const int i0 = bx * 128, j0 = by * 128;
  const int wm = (wave >> 1) * 64, wn = (wave & 1) * 64;

  auto stage = [&](int k0, int buf) {
#pragma unroll
    for (int c = 0; c < 2; ++c) {
      int ch = (wave * 2 + c) * 64 + lane;
      int row = ch >> 2, cg = ch & 3;
      int i = i0 + row, b = i >> 10, s = i & 1023;
      int kcol = k0 + cg * 8, h = kcol >> 6, dd = kcol & 63;
      async16(Oh + (((size_t)b * 16 + h) * SS + s) * 64 + dd, &At[buf][0] + (wave * 2 + c) * 512);
      async16(Wob + (size_t)(j0 + row) * 1024 + k0 + cg * 8, &Bt[buf][0] + (wave * 2 + c) * 512);
    }
  };

  f32x4 acc[4][4];
#pragma unroll
  for (int m = 0; m < 4; ++m)
#pragma unroll
    for (int n = 0; n < 4; ++n) acc[m][n] = (f32x4){0.f, 0.f, 0.f, 0.f};

  stage(0, 0);
  __syncthreads();

  for (int it = 0; it < 32; ++it) {
    const int cur = it & 1, nxt = cur ^ 1;
    if (it < 31) stage((it + 1) * 32, nxt);
    bf16x8 af[4], bf[4];
#pragma unroll
    for (int m = 0; m < 4; ++m)
      af[m] = *(const bf16x8*)(&At[cur][(wm + m * 16 + r15) * 32 + g4 * 8]);
#pragma unroll
    for (int n = 0; n < 4; ++n)
      bf[n] = *(const bf16x8*)(&Bt[cur][(wn + n * 16 + r15) * 32 + g4 * 8]);
    __builtin_amdgcn_s_setprio(1);
#pragma unroll
    for (int m = 0; m < 4; ++m)
#pragma unroll
      for (int n = 0; n < 4; ++n)
        acc[m][n] = __builtin_amdgcn_mfma_f32_16x16x32_bf16(af[m], bf[n], acc[m][n], 0, 0, 0);
    __builtin_amdgcn_s_setprio(0);
    __syncthreads();
  }

#pragma unroll
  for (int m = 0; m < 4; ++m)
#pragma unroll
    for (int n = 0; n < 4; ++n)
#pragma unroll
      for (int r = 0; r < 4; ++r) {
        int i = i0 + wm + m * 16 + g4 * 4 + r;
        int j = j0 + wn + n * 16 + r15;
        Out[(size_t)i * 1024 + j] = acc[m][n][r];
      }
}

// ---------------- merged pos transpose-copy + zero pad + V' build ----------------
__global__ __launch_bounds__(256) void pos_vp(unsigned short* __restrict__ Qt,
                                              unsigned short* __restrict__ Kt,
                                              const float* __restrict__ cpe,
                                              const float* __restrict__ cpp,
                                              const float* __restrict__ pe,
                                              const float* __restrict__ pp,
                                              const unsigned short* __restrict__ Vp,
                                              const float* __restrict__ relv,
                                              unsigned short* __restrict__ VpT) {
  const int z = blockIdx.z;
  unsigned short* T = z ? Kt : Qt;
  const float* Pe = z ? pe : cpe;
  const float* Pp = z ? pp : cpp;
  const int cbase = z ? 64 : 98;
  const float scale = z ? 1.0f : KAPPA;
  const int bh = blockIdx.y, h = bh & 15, s0 = blockIdx.x * 64;
  const int tid = threadIdx.x;
  __shared__ float PeL[17][65];
  __shared__ float PpL[17][65];
  __shared__ unsigned short VT[64][72];

  for (int idx = tid; idx < 17 * 64; idx += 256) {
    int r = idx >> 6, c = idx & 63;
    PeL[r][c] = Pe[((size_t)bh * 17 + r) * SS + s0 + c];
    PpL[r][c] = Pp[((size_t)bh * 17 + r) * SS + s0 + c];
  }
  __syncthreads();

  for (int idx = tid; idx < 4096; idx += 256) {
    int s = idx >> 6, j = idx & 63;
    if (j < 34) {
      float v = (j < 17) ? PeL[j][s] : PpL[j - 17][s];
      T[((size_t)bh * SS + s0 + s) * DAUG + cbase + j] = f2b(v * scale);
    } else if (j < 62) {
      T[((size_t)bh * SS + s0 + s) * DAUG + 132 + (j - 34)] = 0;
    }
  }

  if (z == 1) {
    const int d = tid & 63, sg = tid >> 6;
    float acc[16];
#pragma unroll
    for (int si = 0; si < 16; ++si) acc[si] = 0.f;
    for (int r = 0; r < 17; ++r) {
      float ve = relv[((size_t)h * 34 + r) * 64 + d];
      float vpv = relv[((size_t)h * 34 + 17 + r) * 64 + d];
#pragma unroll
      for (int si = 0; si < 16; ++si) {
        int s = sg * 16 + si;
        acc[si] += PeL[r][s] * ve + PpL[r][s] * vpv;
      }
    }
#pragma unroll
    for (int si = 0; si < 16; ++si) {
      int s = sg * 16 + si;
      float v = b2f(Vp[((size_t)bh * SS + s0 + s) * 64 + d]) + acc[si];
      VT[d][s] = f2b(v);
    }
    __syncthreads();

    for (int c = tid; c < 512; c += 256) {
      int row = c >> 3, c8 = c & 7;
      uint4 v = *(const uint4*)&VT[row][c8 * 8];
      *(uint4*)(VpT + ((size_t)bh * 64 + row) * 1024 + s0 + c8 * 8) = v;
    }
  }
}

// ---------------- flash attention v7: 32x32 MFMA, swapped operands, in-lane softmax ------
// 8 waves = 4 q-subtiles (32 rows) x 2 kv-halves (32 cols). S^T = K.Q^T per wave:
// lane holds 32 scores of ONE q-row -> softmax is in-lane + one shfl_xor(32).
// P packed to bf16 in regs; PV computes O^T = V^T.P^T (A=V^T frag from LDS,
// B=P^T frag assembled with 2 shfl_xor(32) per 16-kv slice). kv-halves merged once
// in epilogue (split-K attention merge) via LDS scratch aliased over Ks/Vs.
__global__ __launch_bounds__(512, 4) void flash_attn5(
    const unsigned short* __restrict__ Qt, const unsigned short* __restrict__ Kt,
    const unsigned short* __restrict__ VpT, unsigned short* __restrict__ Oh) {
  const int bh = blockIdx.y;
  const int q0 = blockIdx.x * 128;
  const int tid = threadIdx.x, wave = tid >> 6, lane = tid & 63;
  const int l31 = lane & 31, hi = lane >> 5;
  const int qq = wave & 3, kvh = wave >> 2;

  // Ks: 2 x 64x160 (20480 ush), Vs: 2 x 64x64 (8192 ush) => 28672 ush = 56KB
  __shared__ unsigned short SM[28672];

  const unsigned short* Kbase = Kt + (size_t)bh * SS * DAUG;
  const unsigned short* Vbase = VpT + (size_t)bh * 64 * 1024;

  // hoist Q (B-operand frags): lane covers q-col q0+qq*32+l31, k = kk*16 + hi*8 + e
  bf16x8 qf[10];
  {
    const unsigned short* Qg = Qt + ((size_t)bh * SS + q0 + qq * 32 + l31) * DAUG + hi * 8;
#pragma unroll
    for (int kk = 0; kk < 10; ++kk) qf[kk] = *(const bf16x8*)(Qg + kk * 16);
  }

  auto stageK = [&](int kv0, int buf) {
    const unsigned short* Kg = Kbase + (size_t)kv0 * DAUG;
#pragma unroll
    for (int j = 0; j < 2; ++j) {
      int ibase = j * 512 + wave * 64;
      int i = ibase + lane;
      int row = i / 20, c = i % 20;
      async16(Kg + (size_t)row * DAUG + ksw(c, row) * 8, SM + buf * 10240 + (size_t)ibase * 8);
    }
    if (wave < 4) {
      int ibase = 1024 + wave * 64;
      int i = ibase + lane;
      int row = i / 20, c = i % 20;
      async16(Kg + (size_t)row * DAUG + ksw(c, row) * 8, SM + buf * 10240 + (size_t)ibase * 8);
    }
  };
  auto stageV = [&](int kv0, int buf) {
    int c = tid;  // 512 chunks exactly
    int row = c >> 3, c8 = c & 7;
    async16(Vbase + (size_t)row * 1024 + kv0 + ((c8 ^ (row & 7)) << 3),
            SM + 20480 + buf * 4096 + (size_t)c * 8);
  };

  stageK(0, 0);
  stageV(0, 0);
  __syncthreads();

  f32x16 accO[2];
#pragma unroll
  for (int j = 0; j < 16; ++j) { accO[0][j] = 0.f; accO[1][j] = 0.f; }
  float run_m = -INFINITY, run_l = 0.f;

  const int krow = kvh * 32 + l31;

  for (int t = 0; t < 16; ++t) {
    const int cur = t & 1, nxt = cur ^ 1;
    if (t < 15) {
      stageK((t + 1) * 64, nxt);
      stageV((t + 1) * 64, nxt);
    }

    // S^T = K . Q^T : 32 kv (this half) x 32 q
    f32x16 sT;
#pragma unroll
    for (int j = 0; j < 16; ++j) sT[j] = 0.f;
    __builtin_amdgcn_s_setprio(1);
#pragma unroll
    for (int kk = 0; kk < 10; ++kk) {
      int c = 2 * kk + hi;
      bf16x8 kf = *(const bf16x8*)(SM + cur * 10240 + (size_t)krow * 160 + ksw(c, krow) * 8);
      sT = __builtin_amdgcn_mfma_f32_32x32x16_bf16(kf, qf[kk], sT, 0, 0, 0);
    }
    __builtin_amdgcn_s_setprio(0);

    // in-lane softmax over 32 kv (16 regs + cross-hi exchange)
    float mx = sT[0];
#pragma unroll
    for (int j = 1; j < 16; ++j) mx = fmaxf(mx, sT[j]);
    mx = fmaxf(mx, __shfl_xor(mx, 32, 64));

    bool cond = (mx <= run_m + 8.f);
    if (!__all(cond)) {
      float mnew = fmaxf(run_m, mx);
      float corr = exp2f(run_m - mnew);
      run_m = mnew;
      run_l *= corr;
#pragma unroll
      for (int j = 0; j < 16; ++j) { accO[0][j] *= corr; accO[1][j] *= corr; }
    }
    float lsum = 0.f;
#pragma unroll
    for (int j = 0; j < 16; ++j) {
      float p = exp2f(sT[j] - run_m);
      sT[j] = p;
      lsum += p;
    }
    run_l += lsum + __shfl_xor(lsum, 32, 64);

    // pack P to bf16 pairs (by reg: rows d adjacent)
    uint32_t w[8];
#pragma unroll
    for (int j = 0; j < 8; ++j) w[j] = pk2(sT[2 * j], sT[2 * j + 1]);

    // build B-operand frags per 16-kv slice and do PV
    bf16x8 bfrag[2];
#pragma unroll
    for (int ks = 0; ks < 2; ++ks) {
      int b = ks * 4;
      uint32_t sel_a = hi ? w[b + 0] : w[b + 2];
      uint32_t sel_b = hi ? w[b + 1] : w[b + 3];
      uint32_t x_a = (uint32_t)__shfl_xor((int)sel_a, 32, 64);
      uint32_t x_b = (uint32_t)__shfl_xor((int)sel_b, 32, 64);
      union { uint32_t u[4]; bf16x8 v; } bw;
      bw.u[0] = hi ? x_a : w[b + 0];
      bw.u[1] = hi ? x_b : w[b + 1];
      bw.u[2] = hi ? w[b + 2] : x_a;
      bw.u[3] = hi ? w[b + 3] : x_b;
      bfrag[ks] = bw.v;
    }

    __builtin_amdgcn_s_setprio(1);
#pragma unroll
    for (int dt = 0; dt < 2; ++dt) {
      int vrow = dt * 32 + l31;
#pragma unroll
      for (int ks = 0; ks < 2; ++ks) {
        int c = kvh * 4 + ks * 2 + hi;
        bf16x8 vf = *(const bf16x8*)(SM + 20480 + cur * 4096 + (size_t)vrow * 64 +
                                     ((c ^ (vrow & 7)) << 3));
        accO[dt] = __builtin_amdgcn_mfma_f32_32x32x16_bf16(vf, bfrag[ks], accO[dt], 0, 0, 0);
      }
    }
    __builtin_amdgcn_s_setprio(0);

    __syncthreads();
  }

  // ---- epilogue: merge kv-halves, normalize, coalesced store ----
  float* SC = (float*)SM;            // [p][d 64][q 32] partials from kvh=1
  float* Ml = SC + 8192;             // m per (p, q)
  float* Ll = SC + 8320;             // l per (p, q)
  uint32_t* OT = (uint32_t*)(SC + 8448);  // [128 q][33 u32]

  if (kvh == 1) {
#pragma unroll
    for (int dt = 0; dt < 2; ++dt)
#pragma unroll
      for (int j = 0; j < 16; ++j) {
        int d = (j & 3) + 8 * (j >> 2) + 4 * hi + 32 * dt;
        SC[qq * 2048 + d * 32 + l31] = accO[dt][j];
      }
    if (hi == 0) {
      Ml[qq * 32 + l31] = run_m;
      Ll[qq * 32 + l31] = run_l;
    }
  }
  __syncthreads();
  if (kvh == 0) {
    float m1 = Ml[qq * 32 + l31], l1v = Ll[qq * 32 + l31];
    float M = fmaxf(run_m, m1);
    float c0 = exp2f(run_m - M), c1 = exp2f(m1 - M);
    float inv = 1.f / (run_l * c0 + l1v * c1);
#pragma unroll
    for (int dt = 0; dt < 2; ++dt)
#pragma unroll
      for (int j = 0; j < 16; j += 2) {
        int d = (j & 3) + 8 * (j >> 2) + 4 * hi + 32 * dt;
        float o0 = (accO[dt][j] * c0 + SC[qq * 2048 + d * 32 + l31] * c1) * inv;
        float o1 = (accO[dt][j + 1] * c0 + SC[qq * 2048 + (d + 1) * 32 + l31] * c1) * inv;
        OT[(qq * 32 + l31) * 33 + (d >> 1)] = pk2(o0, o1);
      }
  }
  __syncthreads();
  for (int c = tid; c < 1024; c += 512) {
    int row = c >> 3, ch = c & 7;
    uint4 v;
    v.x = OT[row * 33 + ch * 4 + 0];
    v.y = OT[row * 33 + ch * 4 + 1];
    v.z = OT[row * 33 + ch * 4 + 2];
    v.w = OT[row * 33 + ch * 4 + 3];
    *(uint4*)(Oh + ((size_t)bh * SS + q0 + row) * 64 + ch * 8) = v;
  }
}

extern "C" void kernel_launch(void* const* d_in, const int* in_sizes, int n_in,
                              void* d_out, int out_size, void* d_ws, size_t ws_size,
                              hipStream_t stream) {
  const float* query = (const float*)d_in[0];
  const float* key = (const float*)d_in[1];
  const float* value = (const float*)d_in[2];
  const float* pe = (const float*)d_in[3];
  const float* pp = (const float*)d_in[4];
  const float* cpe = (const float*)d_in[5];
  const float* cpp = (const float*)d_in[6];
  const float* relq = (const float*)d_in[7];
  const float* relk = (const float*)d_in[8];
  const float* relv = (const float*)d_in[9];
  const float* Wq = (const float*)d_in[10];
  const float* Wk = (const float*)d_in[11];
  const float* Wv = (const float*)d_in[12];
  const float* Wo = (const float*)d_in[13];
  float* out = (float*)d_out;
  char* ws = (char*)d_ws;

  unsigned short* Xq = (unsigned short*)(ws + 0);
  unsigned short* Xk = (unsigned short*)(ws + 8388608);
  unsigned short* Xv = (unsigned short*)(ws + 16777216);
  unsigned short* Wqb = (unsigned short*)(ws + 25165824);
  unsigned short* Wkb = (unsigned short*)(ws + 27262976);
  unsigned short* Wvb = (unsigned short*)(ws + 29360128);
  unsigned short* Wob = (unsigned short*)(ws + 31457280);
  unsigned short* Qt = (unsigned short*)(ws + 33554432);
  unsigned short* Kt = (unsigned short*)(ws + 54525952);
  unsigned short* Vp = (unsigned short*)(ws + 75497472);
  unsigned short* Oh = (unsigned short*)(ws + 0);         // alias Xq (dead after proj)
  unsigned short* VpT = (unsigned short*)(ws + 8388608);  // alias Xk/Xv (dead after proj)

  convert7<<<dim3(1024, 7, 1), 256, 0, stream>>>(query, key, value, Wq, Wk, Wv, Wo, Xq, Xk, Xv,
                                                 Wqb, Wkb, Wvb, Wob);
  proj_qkv<<<dim3(32, 8, 3), 256, 0, stream>>>(Xq, Xk, Xv, Wqb, Wkb, Wvb, Qt, Kt, Vp, relk, relq);
  pos_vp<<<dim3(16, 64, 2), 256, 0, stream>>>(Qt, Kt, cpe, cpp, pe, pp, Vp, relv, VpT);
  flash_attn5<<<dim3(8, 64, 1), 512, 0, stream>>>(Qt, Kt, VpT, Oh);
  gemm_out<<<dim3(32, 8, 1), 256, 0, stream>>>(Oh, Wob, out);
}

// Round 10
// 160.888 us; speedup vs baseline: 1.1231x; 1.0458x over previous
//
#include <hip/hip_runtime.h>
#include <hip/hip_bf16.h>
#include <stdint.h>

typedef float f32x4 __attribute__((ext_vector_type(4)));
typedef float f32x16 __attribute__((ext_vector_type(16)));
typedef __bf16 bf16x8 __attribute__((ext_vector_type(8)));

#define NBH 64      // B*H
#define SS 1024     // SQ == SKV
#define DAUG 160    // augmented head dim 132 padded to 160
#define KAPPA 0.18033688011104293f  // 0.125 * log2(e), folded into Q~

static __device__ __forceinline__ unsigned short f2b(float f) {
  union { float f; uint32_t u; } v; v.f = f;
  return (unsigned short)((v.u + 0x7fffu + ((v.u >> 16) & 1u)) >> 16);
}
static __device__ __forceinline__ float b2f(unsigned short s) {
  union { uint32_t u; float f; } v; v.u = ((uint32_t)s) << 16;
  return v.f;
}
static __device__ __forceinline__ uint32_t pk2(float a, float b) {
  return (uint32_t)f2b(a) | ((uint32_t)f2b(b) << 16);
}
// HW packed f32->bf16 (RTNE), 1 instr (no builtin on gfx950 — T12 recipe)
static __device__ __forceinline__ uint32_t cvtpk(float lo, float hi) {
  uint32_t r;
  asm("v_cvt_pk_bf16_f32 %0, %1, %2" : "=v"(r) : "v"(lo), "v"(hi));
  return r;
}

static __device__ __forceinline__ void async16(const void* g, void* l) {
  __builtin_amdgcn_global_load_lds(
      (const __attribute__((address_space(1))) uint32_t*)g,
      (__attribute__((address_space(3))) uint32_t*)l, 16, 0, 0);
}

// K-tile chunk swizzle (20 16B-chunks per 160-elem row)
static __device__ __forceinline__ int ksw(int c, int row) {
  return (c < 16) ? (c ^ (row & 7)) : (16 + ((c & 3) ^ (row & 3)));
}

// ---------------- f32 -> bf16 conversion for 7 tensors ----------------
__global__ void convert7(const float* q, const float* k, const float* v,
                         const float* wq, const float* wk, const float* wv, const float* wo,
                         unsigned short* xq, unsigned short* xk, unsigned short* xv,
                         unsigned short* bwq, unsigned short* bwk, unsigned short* bwv,
                         unsigned short* bwo) {
  const float* s; unsigned short* d; int n;
  switch (blockIdx.y) {
    case 0: s = q;  d = xq;  n = 4194304; break;
    case 1: s = k;  d = xk;  n = 4194304; break;
    case 2: s = v;  d = xv;  n = 4194304; break;
    case 3: s = wq; d = bwq; n = 1048576; break;
    case 4: s = wk; d = bwk; n = 1048576; break;
    case 5: s = wv; d = bwv; n = 1048576; break;
    default: s = wo; d = bwo; n = 1048576; break;
  }
  int n4 = n >> 2;
  for (int i = blockIdx.x * blockDim.x + threadIdx.x; i < n4; i += gridDim.x * blockDim.x) {
    float4 f = ((const float4*)s)[i];
    uint2 o;
    o.x = cvtpk(f.x, f.y);
    o.y = cvtpk(f.z, f.w);
    ((uint2*)d)[i] = o;
  }
}

// ---------------- QKV projection GEMM + fused rank-34 augmentation ----------------
__global__ __launch_bounds__(256) void proj_qkv(
    const unsigned short* __restrict__ Xq, const unsigned short* __restrict__ Xk,
    const unsigned short* __restrict__ Xv, const unsigned short* __restrict__ Wqb,
    const unsigned short* __restrict__ Wkb, const unsigned short* __restrict__ Wvb,
    unsigned short* __restrict__ Qt, unsigned short* __restrict__ Kt,
    unsigned short* __restrict__ Vp, const float* __restrict__ relk,
    const float* __restrict__ relq) {
  const int n_ = blockIdx.x + 32 * (blockIdx.y + 8 * blockIdx.z);
  const int o_ = (n_ & 7) * 96 + (n_ >> 3);
  const int bx = o_ & 31, by = (o_ >> 5) & 7, z = o_ >> 8;

  const unsigned short* A = (z == 0) ? Xq : (z == 1) ? Xk : Xv;
  const unsigned short* Bw = (z == 0) ? Wqb : (z == 1) ? Wkb : Wvb;
  unsigned short* Dst = (z == 0) ? Qt : (z == 1) ? Kt : Vp;
  const int dstride = (z == 2) ? 64 : DAUG;
  const float sc = (z == 0) ? KAPPA : 1.0f;

  __shared__ unsigned short SMEM[23296];
  unsigned short* AtB = SMEM;
  unsigned short* BtB = SMEM + 8192;
  unsigned short* RelL = SMEM + 16384;
  unsigned short* Ys = SMEM;

  const int tid = threadIdx.x, wave = tid >> 6, lane = tid & 63;
  const int r15 = lane & 15, g4 = lane >> 4;
  const int i0 = bx * 128, j0 = by * 128;
  const int wm = (wave >> 1) * 64, wn = (wave & 1) * 64;

  if (z < 2) {
    const float* rel = (z == 0) ? relk : relq;
    const int h0 = by * 2;
    for (int idx = tid; idx < 2 * 48 * 64; idx += 256) {
      int hh = idx / (48 * 64), rem = idx % (48 * 64);
      int r = rem >> 6, d = rem & 63;
      float v = (r < 34) ? rel[(((size_t)(h0 + hh)) * 34 + r) * 64 + d] : 0.f;
      RelL[(hh * 48 + r) * 72 + d] = f2b(v);
    }
  }

  auto stage = [&](int k0, int buf) {
#pragma unroll
    for (int c = 0; c < 2; ++c) {
      int ch = (wave * 2 + c) * 64 + lane;
      int row = ch >> 2, cg = ch & 3;
      async16(A + (size_t)(i0 + row) * 1024 + k0 + cg * 8, AtB + buf * 4096 + (wave * 2 + c) * 512);
      async16(Bw + (size_t)(j0 + row) * 1024 + k0 + cg * 8, BtB + buf * 4096 + (wave * 2 + c) * 512);
    }
  };

  f32x4 acc[4][4];
#pragma unroll
  for (int m = 0; m < 4; ++m)
#pragma unroll
    for (int n = 0; n < 4; ++n) acc[m][n] = (f32x4){0.f, 0.f, 0.f, 0.f};

  stage(0, 0);
  __syncthreads();

  for (int it = 0; it < 32; ++it) {
    const int cur = it & 1, nxt = cur ^ 1;
    if (it < 31) stage((it + 1) * 32, nxt);
    bf16x8 af[4], bf[4];
#pragma unroll
    for (int m = 0; m < 4; ++m)
      af[m] = *(const bf16x8*)(AtB + cur * 4096 + (wm + m * 16 + r15) * 32 + g4 * 8);
#pragma unroll
    for (int n = 0; n < 4; ++n)
      bf[n] = *(const bf16x8*)(BtB + cur * 4096 + (wn + n * 16 + r15) * 32 + g4 * 8);
    __builtin_amdgcn_s_setprio(1);
#pragma unroll
    for (int m = 0; m < 4; ++m)
#pragma unroll
      for (int n = 0; n < 4; ++n)
        acc[m][n] = __builtin_amdgcn_mfma_f32_16x16x32_bf16(af[m], bf[n], acc[m][n], 0, 0, 0);
    __builtin_amdgcn_s_setprio(0);
    __syncthreads();
  }

#pragma unroll
  for (int m = 0; m < 4; ++m)
#pragma unroll
    for (int n = 0; n < 4; ++n)
#pragma unroll
      for (int r = 0; r < 4; ++r) {
        int lrow = wm + m * 16 + g4 * 4 + r;
        int lcol = wn + n * 16 + r15;
        int i = i0 + lrow, j = j0 + lcol;
        float y = acc[m][n][r] * sc;
        int b = i >> 10, s = i & 1023, h = j >> 6, d = j & 63;
        Dst[(((size_t)b * 16 + h) * SS + s) * dstride + d] = f2b(y);
        if (z < 2) {
          int c8 = (lcol >> 3) ^ (lrow & 7);
          Ys[lrow * 128 + c8 * 8 + (lcol & 7)] = f2b(y);
        }
      }

  if (z < 2) {
    const int cbase = (z == 0) ? 64 : 98;
    __syncthreads();
#pragma unroll
    for (int hh = 0; hh < 2; ++hh) {
      bf16x8 bfr[3][2];
#pragma unroll
      for (int n = 0; n < 3; ++n)
#pragma unroll
        for (int st = 0; st < 2; ++st)
          bfr[n][st] = *(const bf16x8*)(RelL + (hh * 48 + n * 16 + r15) * 72 + st * 32 + g4 * 8);

      f32x4 a2[2][3];
#pragma unroll
      for (int m2 = 0; m2 < 2; ++m2)
#pragma unroll
        for (int n = 0; n < 3; ++n) a2[m2][n] = (f32x4){0.f, 0.f, 0.f, 0.f};

#pragma unroll
      for (int m2 = 0; m2 < 2; ++m2) {
        int lrow = wave * 32 + m2 * 16 + r15;
        int c8a = (hh * 8 + 0 * 4 + g4) ^ (lrow & 7);
        int c8b = (hh * 8 + 1 * 4 + g4) ^ (lrow & 7);
        bf16x8 a0 = *(const bf16x8*)(Ys + lrow * 128 + c8a * 8);
        bf16x8 a1 = *(const bf16x8*)(Ys + lrow * 128 + c8b * 8);
#pragma unroll
        for (int n = 0; n < 3; ++n) {
          a2[m2][n] = __builtin_amdgcn_mfma_f32_16x16x32_bf16(a0, bfr[n][0], a2[m2][n], 0, 0, 0);
          a2[m2][n] = __builtin_amdgcn_mfma_f32_16x16x32_bf16(a1, bfr[n][1], a2[m2][n], 0, 0, 0);
        }
      }

      const int h = by * 2 + hh;
#pragma unroll
      for (int m2 = 0; m2 < 2; ++m2)
#pragma unroll
        for (int n = 0; n < 3; ++n) {
          int col = n * 16 + r15;
          if (col < 34) {
#pragma unroll
            for (int rr = 0; rr < 4; ++rr) {
              int i = i0 + wave * 32 + m2 * 16 + g4 * 4 + rr;
              int b = i >> 10, s = i & 1023;
              Dst[(((size_t)b * 16 + h) * SS + s) * DAUG + cbase + col] = f2b(a2[m2][n][rr]);
            }
          }
        }
    }
  }
}

// ---------------- output projection GEMM ----------------
__global__ __launch_bounds__(256) void gemm_out(const unsigned short* __restrict__ Oh,
                                                const unsigned short* __restrict__ Wob,
                                                float* __restrict__ Out) {
  const int n_ = blockIdx.x + 32 * blockIdx.y;
  const int o_ = (n_ & 7) * 32 + (n_ >> 3);
  const int bx = o_ & 31, by = o_ >> 5;

  __shared__ unsigned short At[2][128 * 32];
  __shared__ unsigned short Bt[2][128 * 32];

  const int tid = threadIdx.x, wave = tid >> 6, lane = tid & 63;
  const int r15 = lane & 15, g4 = lane >> 4;
  const int i0 = bx * 128, j0 = by * 128;
  const int wm = (wave >> 1) * 64, wn = (wave & 1) * 64;

  auto stage = [&](int k0, int buf) {
#pragma unroll
    for (int c = 0; c < 2; ++c) {
      int ch = (wave * 2 + c) * 64 + lane;
      int row = ch >> 2, cg = ch & 3;
      int i = i0 + row, b = i >> 10, s = i & 1023;
      int kcol = k0 + cg * 8, h = kcol >> 6, dd = kcol & 63;
      async16(Oh + (((size_t)b * 16 + h) * SS + s) * 64 + dd, &At[buf][0] + (wave * 2 + c) * 512);
      async16(Wob + (size_t)(j0 + row) * 1024 + k0 + cg * 8, &Bt[buf][0] + (wave * 2 + c) * 512);
    }
  };

  f32x4 acc[4][4];
#pragma unroll
  for (int m = 0; m < 4; ++m)
#pragma unroll
    for (int n = 0; n < 4; ++n) acc[m][n] = (f32x4){0.f, 0.f, 0.f, 0.f};

  stage(0, 0);
  __syncthreads();

  for (int it = 0; it < 32; ++it) {
    const int cur = it & 1, nxt = cur ^ 1;
    if (it < 31) stage((it + 1) * 32, nxt);
    bf16x8 af[4], bf[4];
#pragma unroll
    for (int m = 0; m < 4; ++m)
      af[m] = *(const bf16x8*)(&At[cur][(wm + m * 16 + r15) * 32 + g4 * 8]);
#pragma unroll
    for (int n = 0; n < 4; ++n)
      bf[n] = *(const bf16x8*)(&Bt[cur][(wn + n * 16 + r15) * 32 + g4 * 8]);
    __builtin_amdgcn_s_setprio(1);
#pragma unroll
    for (int m = 0; m < 4; ++m)
#pragma unroll
      for (int n = 0; n < 4; ++n)
        acc[m][n] = __builtin_amdgcn_mfma_f32_16x16x32_bf16(af[m], bf[n], acc[m][n], 0, 0, 0);
    __builtin_amdgcn_s_setprio(0);
    __syncthreads();
  }

#pragma unroll
  for (int m = 0; m < 4; ++m)
#pragma unroll
    for (int n = 0; n < 4; ++n)
#pragma unroll
      for (int r = 0; r < 4; ++r) {
        int i = i0 + wm + m * 16 + g4 * 4 + r;
        int j = j0 + wn + n * 16 + r15;
        Out[(size_t)i * 1024 + j] = acc[m][n][r];
      }
}

// ---------------- merged pos transpose-copy + zero pad + V' build ----------------
__global__ __launch_bounds__(256) void pos_vp(unsigned short* __restrict__ Qt,
                                              unsigned short* __restrict__ Kt,
                                              const float* __restrict__ cpe,
                                              const float* __restrict__ cpp,
                                              const float* __restrict__ pe,
                                              const float* __restrict__ pp,
                                              const unsigned short* __restrict__ Vp,
                                              const float* __restrict__ relv,
                                              unsigned short* __restrict__ VpT) {
  const int z = blockIdx.z;
  unsigned short* T = z ? Kt : Qt;
  const float* Pe = z ? pe : cpe;
  const float* Pp = z ? pp : cpp;
  const int cbase = z ? 64 : 98;
  const float scale = z ? 1.0f : KAPPA;
  const int bh = blockIdx.y, h = bh & 15, s0 = blockIdx.x * 64;
  const int tid = threadIdx.x;
  __shared__ float PeL[17][65];
  __shared__ float PpL[17][65];
  __shared__ unsigned short VT[64][72];

  for (int idx = tid; idx < 17 * 64; idx += 256) {
    int r = idx >> 6, c = idx & 63;
    PeL[r][c] = Pe[((size_t)bh * 17 + r) * SS + s0 + c];
    PpL[r][c] = Pp[((size_t)bh * 17 + r) * SS + s0 + c];
  }
  __syncthreads();

  for (int idx = tid; idx < 4096; idx += 256) {
    int s = idx >> 6, j = idx & 63;
    if (j < 34) {
      float v = (j < 17) ? PeL[j][s] : PpL[j - 17][s];
      T[((size_t)bh * SS + s0 + s) * DAUG + cbase + j] = f2b(v * scale);
    } else if (j < 62) {
      T[((size_t)bh * SS + s0 + s) * DAUG + 132 + (j - 34)] = 0;
    }
  }

  if (z == 1) {
    const int d = tid & 63, sg = tid >> 6;
    float acc[16];
#pragma unroll
    for (int si = 0; si < 16; ++si) acc[si] = 0.f;
    for (int r = 0; r < 17; ++r) {
      float ve = relv[((size_t)h * 34 + r) * 64 + d];
      float vpv = relv[((size_t)h * 34 + 17 + r) * 64 + d];
#pragma unroll
      for (int si = 0; si < 16; ++si) {
        int s = sg * 16 + si;
        acc[si] += PeL[r][s] * ve + PpL[r][s] * vpv;
      }
    }
#pragma unroll
    for (int si = 0; si < 16; ++si) {
      int s = sg * 16 + si;
      float v = b2f(Vp[((size_t)bh * SS + s0 + s) * 64 + d]) + acc[si];
      VT[d][s] = f2b(v);
    }
    __syncthreads();

    for (int c = tid; c < 512; c += 256) {
      int row = c >> 3, c8 = c & 7;
      uint4 v = *(const uint4*)&VT[row][c8 * 8];
      *(uint4*)(VpT + ((size_t)bh * 64 + row) * 1024 + s0 + c8 * 8) = v;
    }
  }
}

// ---------------- flash attention v8: v7 + cvt_pk pack + max3 tree + XCD swizzle --------
__global__ __launch_bounds__(512, 4) void flash_attn5(
    const unsigned short* __restrict__ Qt, const unsigned short* __restrict__ Kt,
    const unsigned short* __restrict__ VpT, unsigned short* __restrict__ Oh) {
  // T1 bijective XCD swizzle: 512 blocks; each XCD owns 8 consecutive bh (all
  // their q-blocks) so shared K/V/Q panels (~6MB) stay in that XCD's L2.
  const int n_ = blockIdx.x + 8 * blockIdx.y;
  const int o_ = (n_ & 7) * 64 + (n_ >> 3);
  const int bh = o_ >> 3;
  const int q0 = (o_ & 7) * 128;
  const int tid = threadIdx.x, wave = tid >> 6, lane = tid & 63;
  const int l31 = lane & 31, hi = lane >> 5;
  const int qq = wave & 3, kvh = wave >> 2;

  __shared__ unsigned short SM[28672];

  const unsigned short* Kbase = Kt + (size_t)bh * SS * DAUG;
  const unsigned short* Vbase = VpT + (size_t)bh * 64 * 1024;

  bf16x8 qf[10];
  {
    const unsigned short* Qg = Qt + ((size_t)bh * SS + q0 + qq * 32 + l31) * DAUG + hi * 8;
#pragma unroll
    for (int kk = 0; kk < 10; ++kk) qf[kk] = *(const bf16x8*)(Qg + kk * 16);
  }

  auto stageK = [&](int kv0, int buf) {
    const unsigned short* Kg = Kbase + (size_t)kv0 * DAUG;
#pragma unroll
    for (int j = 0; j < 2; ++j) {
      int ibase = j * 512 + wave * 64;
      int i = ibase + lane;
      int row = i / 20, c = i % 20;
      async16(Kg + (size_t)row * DAUG + ksw(c, row) * 8, SM + buf * 10240 + (size_t)ibase * 8);
    }
    if (wave < 4) {
      int ibase = 1024 + wave * 64;
      int i = ibase + lane;
      int row = i / 20, c = i % 20;
      async16(Kg + (size_t)row * DAUG + ksw(c, row) * 8, SM + buf * 10240 + (size_t)ibase * 8);
    }
  };
  auto stageV = [&](int kv0, int buf) {
    int c = tid;
    int row = c >> 3, c8 = c & 7;
    async16(Vbase + (size_t)row * 1024 + kv0 + ((c8 ^ (row & 7)) << 3),
            SM + 20480 + buf * 4096 + (size_t)c * 8);
  };

  stageK(0, 0);
  stageV(0, 0);
  __syncthreads();

  f32x16 accO[2];
#pragma unroll
  for (int j = 0; j < 16; ++j) { accO[0][j] = 0.f; accO[1][j] = 0.f; }
  float run_m = -INFINITY, run_l = 0.f;

  const int krow = kvh * 32 + l31;

  for (int t = 0; t < 16; ++t) {
    const int cur = t & 1, nxt = cur ^ 1;
    if (t < 15) {
      stageK((t + 1) * 64, nxt);
      stageV((t + 1) * 64, nxt);
    }

    // S^T = K . Q^T : 32 kv (this half) x 32 q
    f32x16 sT;
#pragma unroll
    for (int j = 0; j < 16; ++j) sT[j] = 0.f;
    __builtin_amdgcn_s_setprio(1);
#pragma unroll
    for (int kk = 0; kk < 10; ++kk) {
      int c = 2 * kk + hi;
      bf16x8 kf = *(const bf16x8*)(SM + cur * 10240 + (size_t)krow * 160 + ksw(c, krow) * 8);
      sT = __builtin_amdgcn_mfma_f32_32x32x16_bf16(kf, qf[kk], sT, 0, 0, 0);
    }
    __builtin_amdgcn_s_setprio(0);

    // in-lane max via v_max3-friendly triples (8 ops, depth 3)
    float a0 = fmaxf(fmaxf(sT[0], sT[1]), sT[2]);
    float a1 = fmaxf(fmaxf(sT[3], sT[4]), sT[5]);
    float a2 = fmaxf(fmaxf(sT[6], sT[7]), sT[8]);
    float a3 = fmaxf(fmaxf(sT[9], sT[10]), sT[11]);
    float a4 = fmaxf(fmaxf(sT[12], sT[13]), sT[14]);
    float b0 = fmaxf(fmaxf(a0, a1), a2);
    float b1 = fmaxf(fmaxf(a3, a4), sT[15]);
    float mx = fmaxf(b0, b1);
    mx = fmaxf(mx, __shfl_xor(mx, 32, 64));

    bool cond = (mx <= run_m + 8.f);
    if (!__all(cond)) {
      float mnew = fmaxf(run_m, mx);
      float corr = exp2f(run_m - mnew);
      run_m = mnew;
      run_l *= corr;
#pragma unroll
      for (int j = 0; j < 16; ++j) { accO[0][j] *= corr; accO[1][j] *= corr; }
    }
    float lsum = 0.f;
#pragma unroll
    for (int j = 0; j < 16; ++j) {
      float p = exp2f(sT[j] - run_m);
      sT[j] = p;
      lsum += p;
    }
    run_l += lsum + __shfl_xor(lsum, 32, 64);

    // pack P to bf16 pairs via HW cvt_pk (T12): 8 instrs instead of ~48 VALU ops
    uint32_t w[8];
#pragma unroll
    for (int j = 0; j < 8; ++j) w[j] = cvtpk(sT[2 * j], sT[2 * j + 1]);

    // build B-operand frags per 16-kv slice and do PV
    bf16x8 bfrag[2];
#pragma unroll
    for (int ks = 0; ks < 2; ++ks) {
      int b = ks * 4;
      uint32_t sel_a = hi ? w[b + 0] : w[b + 2];
      uint32_t sel_b = hi ? w[b + 1] : w[b + 3];
      uint32_t x_a = (uint32_t)__shfl_xor((int)sel_a, 32, 64);
      uint32_t x_b = (uint32_t)__shfl_xor((int)sel_b, 32, 64);
      union { uint32_t u[4]; bf16x8 v; } bw;
      bw.u[0] = hi ? x_a : w[b + 0];
      bw.u[1] = hi ? x_b : w[b + 1];
      bw.u[2] = hi ? w[b + 2] : x_a;
      bw.u[3] = hi ? w[b + 3] : x_b;
      bfrag[ks] = bw.v;
    }

    __builtin_amdgcn_s_setprio(1);
#pragma unroll
    for (int dt = 0; dt < 2; ++dt) {
      int vrow = dt * 32 + l31;
#pragma unroll
      for (int ks = 0; ks < 2; ++ks) {
        int c = kvh * 4 + ks * 2 + hi;
        bf16x8 vf = *(const bf16x8*)(SM + 20480 + cur * 4096 + (size_t)vrow * 64 +
                                     ((c ^ (vrow & 7)) << 3));
        accO[dt] = __builtin_amdgcn_mfma_f32_32x32x16_bf16(vf, bfrag[ks], accO[dt], 0, 0, 0);
      }
    }
    __builtin_amdgcn_s_setprio(0);

    __syncthreads();
  }

  // ---- epilogue: merge kv-halves, normalize, coalesced store ----
  float* SC = (float*)SM;
  float* Ml = SC + 8192;
  float* Ll = SC + 8320;
  uint32_t* OT = (uint32_t*)(SC + 8448);

  if (kvh == 1) {
#pragma unroll
    for (int dt = 0; dt < 2; ++dt)
#pragma unroll
      for (int j = 0; j < 16; ++j) {
        int d = (j & 3) + 8 * (j >> 2) + 4 * hi + 32 * dt;
        SC[qq * 2048 + d * 32 + l31] = accO[dt][j];
      }
    if (hi == 0) {
      Ml[qq * 32 + l31] = run_m;
      Ll[qq * 32 + l31] = run_l;
    }
  }
  __syncthreads();
  if (kvh == 0) {
    float m1 = Ml[qq * 32 + l31], l1v = Ll[qq * 32 + l31];
    float M = fmaxf(run_m, m1);
    float c0 = exp2f(run_m - M), c1 = exp2f(m1 - M);
    float inv = 1.f / (run_l * c0 + l1v * c1);
#pragma unroll
    for (int dt = 0; dt < 2; ++dt)
#pragma unroll
      for (int j = 0; j < 16; j += 2) {
        int d = (j & 3) + 8 * (j >> 2) + 4 * hi + 32 * dt;
        float o0 = (accO[dt][j] * c0 + SC[qq * 2048 + d * 32 + l31] * c1) * inv;
        float o1 = (accO[dt][j + 1] * c0 + SC[qq * 2048 + (d + 1) * 32 + l31] * c1) * inv;
        OT[(qq * 32 + l31) * 33 + (d >> 1)] = pk2(o0, o1);
      }
  }
  __syncthreads();
  for (int c = tid; c < 1024; c += 512) {
    int row = c >> 3, ch = c & 7;
    uint4 v;
    v.x = OT[row * 33 + ch * 4 + 0];
    v.y = OT[row * 33 + ch * 4 + 1];
    v.z = OT[row * 33 + ch * 4 + 2];
    v.w = OT[row * 33 + ch * 4 + 3];
    *(uint4*)(Oh + ((size_t)bh * SS + q0 + row) * 64 + ch * 8) = v;
  }
}

extern "C" void kernel_launch(void* const* d_in, const int* in_sizes, int n_in,
                              void* d_out, int out_size, void* d_ws, size_t ws_size,
                              hipStream_t stream) {
  const float* query = (const float*)d_in[0];
  const float* key = (const float*)d_in[1];
  const float* value = (const float*)d_in[2];
  const float* pe = (const float*)d_in[3];
  const float* pp = (const float*)d_in[4];
  const float* cpe = (const float*)d_in[5];
  const float* cpp = (const float*)d_in[6];
  const float* relq = (const float*)d_in[7];
  const float* relk = (const float*)d_in[8];
  const float* relv = (const float*)d_in[9];
  const float* Wq = (const float*)d_in[10];
  const float* Wk = (const float*)d_in[11];
  const float* Wv = (const float*)d_in[12];
  const float* Wo = (const float*)d_in[13];
  float* out = (float*)d_out;
  char* ws = (char*)d_ws;

  unsigned short* Xq = (unsigned short*)(ws + 0);
  unsigned short* Xk = (unsigned short*)(ws + 8388608);
  unsigned short* Xv = (unsigned short*)(ws + 16777216);
  unsigned short* Wqb = (unsigned short*)(ws + 25165824);
  unsigned short* Wkb = (unsigned short*)(ws + 27262976);
  unsigned short* Wvb = (unsigned short*)(ws + 29360128);
  unsigned short* Wob = (unsigned short*)(ws + 31457280);
  unsigned short* Qt = (unsigned short*)(ws + 33554432);
  unsigned short* Kt = (unsigned short*)(ws + 54525952);
  unsigned short* Vp = (unsigned short*)(ws + 75497472);
  unsigned short* Oh = (unsigned short*)(ws + 0);         // alias Xq (dead after proj)
  unsigned short* VpT = (unsigned short*)(ws + 8388608);  // alias Xk/Xv (dead after proj)

  convert7<<<dim3(1024, 7, 1), 256, 0, stream>>>(query, key, value, Wq, Wk, Wv, Wo, Xq, Xk, Xv,
                                                 Wqb, Wkb, Wvb, Wob);
  proj_qkv<<<dim3(32, 8, 3), 256, 0, stream>>>(Xq, Xk, Xv, Wqb, Wkb, Wvb, Qt, Kt, Vp, relk, relq);
  pos_vp<<<dim3(16, 64, 2), 256, 0, stream>>>(Qt, Kt, cpe, cpp, pe, pp, Vp, relv, VpT);
  flash_attn5<<<dim3(8, 64, 1), 512, 0, stream>>>(Qt, Kt, VpT, Oh);
  gemm_out<<<dim3(32, 8, 1), 256, 0, stream>>>(Oh, Wob, out);
}

// Round 13
// 155.374 us; speedup vs baseline: 1.1630x; 1.0355x over previous
//
#include <hip/hip_runtime.h>
#include <hip/hip_bf16.h>
#include <stdint.h>

typedef float f32x4 __attribute__((ext_vector_type(4)));
typedef float f32x16 __attribute__((ext_vector_type(16)));
typedef __bf16 bf16x8 __attribute__((ext_vector_type(8)));

#define NBH 64      // B*H
#define SS 1024     // SQ == SKV
#define DAUG 160    // augmented head dim 132 padded to 160
#define KAPPA 0.18033688011104293f  // 0.125 * log2(e), folded into Q~

static __device__ __forceinline__ unsigned short f2b(float f) {
  union { float f; uint32_t u; } v; v.f = f;
  return (unsigned short)((v.u + 0x7fffu + ((v.u >> 16) & 1u)) >> 16);
}
static __device__ __forceinline__ float b2f(unsigned short s) {
  union { uint32_t u; float f; } v; v.u = ((uint32_t)s) << 16;
  return v.f;
}
static __device__ __forceinline__ uint32_t pk2(float a, float b) {
  return (uint32_t)f2b(a) | ((uint32_t)f2b(b) << 16);
}
// HW packed f32->bf16 (RTNE), 1 instr (no builtin on gfx950 - T12 recipe)
static __device__ __forceinline__ uint32_t cvtpk(float lo, float hi) {
  uint32_t r;
  asm("v_cvt_pk_bf16_f32 %0, %1, %2" : "=v"(r) : "v"(lo), "v"(hi));
  return r;
}

static __device__ __forceinline__ void async16(const void* g, void* l) {
  __builtin_amdgcn_global_load_lds(
      (const __attribute__((address_space(1))) uint32_t*)g,
      (__attribute__((address_space(3))) uint32_t*)l, 16, 0, 0);
}

// K-tile chunk swizzle (20 16B-chunks per 160-elem row)
static __device__ __forceinline__ int ksw(int c, int row) {
  return (c < 16) ? (c ^ (row & 7)) : (16 + ((c & 3) ^ (row & 3)));
}

// ---------------- f32 -> bf16 conversion for 7 tensors ----------------
__global__ void convert7(const float* q, const float* k, const float* v,
                         const float* wq, const float* wk, const float* wv, const float* wo,
                         unsigned short* xq, unsigned short* xk, unsigned short* xv,
                         unsigned short* bwq, unsigned short* bwk, unsigned short* bwv,
                         unsigned short* bwo) {
  const float* s; unsigned short* d; int n;
  switch (blockIdx.y) {
    case 0: s = q;  d = xq;  n = 4194304; break;
    case 1: s = k;  d = xk;  n = 4194304; break;
    case 2: s = v;  d = xv;  n = 4194304; break;
    case 3: s = wq; d = bwq; n = 1048576; break;
    case 4: s = wk; d = bwk; n = 1048576; break;
    case 5: s = wv; d = bwv; n = 1048576; break;
    default: s = wo; d = bwo; n = 1048576; break;
  }
  int n4 = n >> 2;
  for (int i = blockIdx.x * blockDim.x + threadIdx.x; i < n4; i += gridDim.x * blockDim.x) {
    float4 f = ((const float4*)s)[i];
    uint2 o;
    o.x = cvtpk(f.x, f.y);
    o.y = cvtpk(f.z, f.w);
    ((uint2*)d)[i] = o;
  }
}

// ---------------- QKV projection GEMM + fused rank-34 augmentation ----------------
// LDS = 32KB only (dbuf, reused as Ys) -> 5 blocks/CU. rel frags loaded from
// global at epilogue (L2-hot, r>=34 zeroed).
__global__ __launch_bounds__(256) void proj_qkv(
    const unsigned short* __restrict__ Xq, const unsigned short* __restrict__ Xk,
    const unsigned short* __restrict__ Xv, const unsigned short* __restrict__ Wqb,
    const unsigned short* __restrict__ Wkb, const unsigned short* __restrict__ Wvb,
    unsigned short* __restrict__ Qt, unsigned short* __restrict__ Kt,
    unsigned short* __restrict__ Vp, const float* __restrict__ relk,
    const float* __restrict__ relq) {
  const int n_ = blockIdx.x + 32 * (blockIdx.y + 8 * blockIdx.z);
  const int o_ = (n_ & 7) * 96 + (n_ >> 3);
  const int bx = o_ & 31, by = (o_ >> 5) & 7, z = o_ >> 8;

  const unsigned short* A = (z == 0) ? Xq : (z == 1) ? Xk : Xv;
  const unsigned short* Bw = (z == 0) ? Wqb : (z == 1) ? Wkb : Wvb;
  unsigned short* Dst = (z == 0) ? Qt : (z == 1) ? Kt : Vp;
  const int dstride = (z == 2) ? 64 : DAUG;
  const float sc = (z == 0) ? KAPPA : 1.0f;

  __shared__ unsigned short SMEM[16384];  // dbuf At/Bt; after K-loop: Ys 128x128
  unsigned short* AtB = SMEM;
  unsigned short* BtB = SMEM + 8192;
  unsigned short* Ys = SMEM;

  const int tid = threadIdx.x, wave = tid >> 6, lane = tid & 63;
  const int r15 = lane & 15, g4 = lane >> 4;
  const int i0 = bx * 128, j0 = by * 128;
  const int wm = (wave >> 1) * 64, wn = (wave & 1) * 64;

  auto stage = [&](int k0, int buf) {
#pragma unroll
    for (int c = 0; c < 2; ++c) {
      int ch = (wave * 2 + c) * 64 + lane;
      int row = ch >> 2, cg = ch & 3;
      async16(A + (size_t)(i0 + row) * 1024 + k0 + cg * 8, AtB + buf * 4096 + (wave * 2 + c) * 512);
      async16(Bw + (size_t)(j0 + row) * 1024 + k0 + cg * 8, BtB + buf * 4096 + (wave * 2 + c) * 512);
    }
  };

  f32x4 acc[4][4];
#pragma unroll
  for (int m = 0; m < 4; ++m)
#pragma unroll
    for (int n = 0; n < 4; ++n) acc[m][n] = (f32x4){0.f, 0.f, 0.f, 0.f};

  stage(0, 0);
  __syncthreads();

  for (int it = 0; it < 32; ++it) {
    const int cur = it & 1, nxt = cur ^ 1;
    if (it < 31) stage((it + 1) * 32, nxt);
    bf16x8 af[4], bf[4];
#pragma unroll
    for (int m = 0; m < 4; ++m)
      af[m] = *(const bf16x8*)(AtB + cur * 4096 + (wm + m * 16 + r15) * 32 + g4 * 8);
#pragma unroll
    for (int n = 0; n < 4; ++n)
      bf[n] = *(const bf16x8*)(BtB + cur * 4096 + (wn + n * 16 + r15) * 32 + g4 * 8);
    __builtin_amdgcn_s_setprio(1);
#pragma unroll
    for (int m = 0; m < 4; ++m)
#pragma unroll
      for (int n = 0; n < 4; ++n)
        acc[m][n] = __builtin_amdgcn_mfma_f32_16x16x32_bf16(af[m], bf[n], acc[m][n], 0, 0, 0);
    __builtin_amdgcn_s_setprio(0);
    __syncthreads();
  }

  // main epilogue: write d-columns to global; z<2 also deposits Y-tile in LDS.
#pragma unroll
  for (int m = 0; m < 4; ++m)
#pragma unroll
    for (int n = 0; n < 4; ++n)
#pragma unroll
      for (int r = 0; r < 4; ++r) {
        int lrow = wm + m * 16 + g4 * 4 + r;
        int lcol = wn + n * 16 + r15;
        int i = i0 + lrow, j = j0 + lcol;
        float y = acc[m][n][r] * sc;
        int b = i >> 10, s = i & 1023, h = j >> 6, d = j & 63;
        Dst[(((size_t)b * 16 + h) * SS + s) * dstride + d] = f2b(y);
        if (z < 2) {
          int c8 = (lcol >> 3) ^ (lrow & 7);
          Ys[lrow * 128 + c8 * 8 + (lcol & 7)] = f2b(y);
        }
      }

  if (z < 2) {
    const float* rel = (z == 0) ? relk : relq;
    const int cbase = (z == 0) ? 64 : 98;
    const int h0 = by * 2;
    __syncthreads();
#pragma unroll
    for (int hh = 0; hh < 2; ++hh) {
      // load rel fragments straight from global (f32 -> bf16 in regs)
      bf16x8 bfr[3][2];
#pragma unroll
      for (int n = 0; n < 3; ++n) {
        int r = n * 16 + r15;
#pragma unroll
        for (int st = 0; st < 2; ++st) {
          union { uint32_t u[4]; bf16x8 v; } bw;
          if (r < 34) {
            const float* src = rel + (((size_t)(h0 + hh)) * 34 + r) * 64 + st * 32 + g4 * 8;
            float4 f0 = *(const float4*)src;
            float4 f1 = *(const float4*)(src + 4);
            bw.u[0] = cvtpk(f0.x, f0.y);
            bw.u[1] = cvtpk(f0.z, f0.w);
            bw.u[2] = cvtpk(f1.x, f1.y);
            bw.u[3] = cvtpk(f1.z, f1.w);
          } else {
            bw.u[0] = bw.u[1] = bw.u[2] = bw.u[3] = 0u;
          }
          bfr[n][st] = bw.v;
        }
      }

      f32x4 a2[2][3];
#pragma unroll
      for (int m2 = 0; m2 < 2; ++m2)
#pragma unroll
        for (int n = 0; n < 3; ++n) a2[m2][n] = (f32x4){0.f, 0.f, 0.f, 0.f};

#pragma unroll
      for (int m2 = 0; m2 < 2; ++m2) {
        int lrow = wave * 32 + m2 * 16 + r15;
        int c8a = (hh * 8 + 0 * 4 + g4) ^ (lrow & 7);
        int c8b = (hh * 8 + 1 * 4 + g4) ^ (lrow & 7);
        bf16x8 a0 = *(const bf16x8*)(Ys + lrow * 128 + c8a * 8);
        bf16x8 a1 = *(const bf16x8*)(Ys + lrow * 128 + c8b * 8);
#pragma unroll
        for (int n = 0; n < 3; ++n) {
          a2[m2][n] = __builtin_amdgcn_mfma_f32_16x16x32_bf16(a0, bfr[n][0], a2[m2][n], 0, 0, 0);
          a2[m2][n] = __builtin_amdgcn_mfma_f32_16x16x32_bf16(a1, bfr[n][1], a2[m2][n], 0, 0, 0);
        }
      }

      const int h = by * 2 + hh;
#pragma unroll
      for (int m2 = 0; m2 < 2; ++m2)
#pragma unroll
        for (int n = 0; n < 3; ++n) {
          int col = n * 16 + r15;
          if (col < 34) {
#pragma unroll
            for (int rr = 0; rr < 4; ++rr) {
              int i = i0 + wave * 32 + m2 * 16 + g4 * 4 + rr;
              int b = i >> 10, s = i & 1023;
              Dst[(((size_t)b * 16 + h) * SS + s) * DAUG + cbase + col] = f2b(a2[m2][n][rr]);
            }
          }
        }
    }
  }
}

// ---------------- output projection GEMM: 64x128 tile, 512 blocks (2/CU grid) ----------
__global__ __launch_bounds__(256) void gemm_out(const unsigned short* __restrict__ Oh,
                                                const unsigned short* __restrict__ Wob,
                                                float* __restrict__ Out) {
  // bijective XCD swizzle over 512 blocks: each XCD owns one full W-panel (by)
  const int n_ = blockIdx.x + 64 * blockIdx.y;
  const int o_ = (n_ & 7) * 64 + (n_ >> 3);
  const int bx = o_ & 63, by = o_ >> 6;

  __shared__ unsigned short At[2][64 * 32];    // 8KB
  __shared__ unsigned short Bt[2][128 * 32];   // 16KB

  const int tid = threadIdx.x, wave = tid >> 6, lane = tid & 63;
  const int r15 = lane & 15, g4 = lane >> 4;
  const int i0 = bx * 64, j0 = by * 128;
  const int wm = (wave >> 1) * 32, wn = (wave & 1) * 64;

  auto stage = [&](int k0, int buf) {
    {  // A: 256 chunks, one per thread
      int i = tid, row = i >> 2, cg = i & 3;
      int gi = i0 + row, b = gi >> 10, s = gi & 1023;
      int kcol = k0 + cg * 8, h = kcol >> 6, dd = kcol & 63;
      async16(Oh + (((size_t)b * 16 + h) * SS + s) * 64 + dd, &At[buf][0] + (size_t)i * 8);
    }
#pragma unroll
    for (int c2 = 0; c2 < 2; ++c2) {  // B: 512 chunks, two per thread
      int i = c2 * 256 + tid, row = i >> 2, cg = i & 3;
      async16(Wob + (size_t)(j0 + row) * 1024 + k0 + cg * 8, &Bt[buf][0] + (size_t)i * 8);
    }
  };

  f32x4 acc[2][4];
#pragma unroll
  for (int m = 0; m < 2; ++m)
#pragma unroll
    for (int n = 0; n < 4; ++n) acc[m][n] = (f32x4){0.f, 0.f, 0.f, 0.f};

  stage(0, 0);
  __syncthreads();

  for (int it = 0; it < 32; ++it) {
    const int cur = it & 1, nxt = cur ^ 1;
    if (it < 31) stage((it + 1) * 32, nxt);
    bf16x8 af[2], bf[4];
#pragma unroll
    for (int m = 0; m < 2; ++m)
      af[m] = *(const bf16x8*)(&At[cur][(wm + m * 16 + r15) * 32 + g4 * 8]);
#pragma unroll
    for (int n = 0; n < 4; ++n)
      bf[n] = *(const bf16x8*)(&Bt[cur][(wn + n * 16 + r15) * 32 + g4 * 8]);
    __builtin_amdgcn_s_setprio(1);
#pragma unroll
    for (int m = 0; m < 2; ++m)
#pragma unroll
      for (int n = 0; n < 4; ++n)
        acc[m][n] = __builtin_amdgcn_mfma_f32_16x16x32_bf16(af[m], bf[n], acc[m][n], 0, 0, 0);
    __builtin_amdgcn_s_setprio(0);
    __syncthreads();
  }

#pragma unroll
  for (int m = 0; m < 2; ++m)
#pragma unroll
    for (int n = 0; n < 4; ++n)
#pragma unroll
      for (int r = 0; r < 4; ++r) {
        int i = i0 + wm + m * 16 + g4 * 4 + r;
        int j = j0 + wn + n * 16 + r15;
        Out[(size_t)i * 1024 + j] = acc[m][n][r];
      }
}

// ---------------- merged pos transpose-copy + zero pad + V' build ----------------
__global__ __launch_bounds__(256) void pos_vp(unsigned short* __restrict__ Qt,
                                              unsigned short* __restrict__ Kt,
                                              const float* __restrict__ cpe,
                                              const float* __restrict__ cpp,
                                              const float* __restrict__ pe,
                                              const float* __restrict__ pp,
                                              const unsigned short* __restrict__ Vp,
                                              const float* __restrict__ relv,
                                              unsigned short* __restrict__ VpT) {
  const int z = blockIdx.z;
  unsigned short* T = z ? Kt : Qt;
  const float* Pe = z ? pe : cpe;
  const float* Pp = z ? pp : cpp;
  const int cbase = z ? 64 : 98;
  const float scale = z ? 1.0f : KAPPA;
  const int bh = blockIdx.y, h = bh & 15, s0 = blockIdx.x * 64;
  const int tid = threadIdx.x;
  __shared__ float PeL[17][65];
  __shared__ float PpL[17][65];
  __shared__ unsigned short VT[64][72];

  for (int idx = tid; idx < 17 * 64; idx += 256) {
    int r = idx >> 6, c = idx & 63;
    PeL[r][c] = Pe[((size_t)bh * 17 + r) * SS + s0 + c];
    PpL[r][c] = Pp[((size_t)bh * 17 + r) * SS + s0 + c];
  }
  __syncthreads();

  for (int idx = tid; idx < 4096; idx += 256) {
    int s = idx >> 6, j = idx & 63;
    if (j < 34) {
      float v = (j < 17) ? PeL[j][s] : PpL[j - 17][s];
      T[((size_t)bh * SS + s0 + s) * DAUG + cbase + j] = f2b(v * scale);
    } else if (j < 62) {
      T[((size_t)bh * SS + s0 + s) * DAUG + 132 + (j - 34)] = 0;
    }
  }

  if (z == 1) {
    const int d = tid & 63, sg = tid >> 6;
    float acc[16];
#pragma unroll
    for (int si = 0; si < 16; ++si) acc[si] = 0.f;
    for (int r = 0; r < 17; ++r) {
      float ve = relv[((size_t)h * 34 + r) * 64 + d];
      float vpv = relv[((size_t)h * 34 + 17 + r) * 64 + d];
#pragma unroll
      for (int si = 0; si < 16; ++si) {
        int s = sg * 16 + si;
        acc[si] += PeL[r][s] * ve + PpL[r][s] * vpv;
      }
    }
#pragma unroll
    for (int si = 0; si < 16; ++si) {
      int s = sg * 16 + si;
      float v = b2f(Vp[((size_t)bh * SS + s0 + s) * 64 + d]) + acc[si];
      VT[d][s] = f2b(v);
    }
    __syncthreads();

    for (int c = tid; c < 512; c += 256) {
      int row = c >> 3, c8 = c & 7;
      uint4 v = *(const uint4*)&VT[row][c8 * 8];
      *(uint4*)(VpT + ((size_t)bh * 64 + row) * 1024 + s0 + c8 * 8) = v;
    }
  }
}

// ---------------- flash attention v8 (unchanged) ----------------
__global__ __launch_bounds__(512, 4) void flash_attn5(
    const unsigned short* __restrict__ Qt, const unsigned short* __restrict__ Kt,
    const unsigned short* __restrict__ VpT, unsigned short* __restrict__ Oh) {
  const int n_ = blockIdx.x + 8 * blockIdx.y;
  const int o_ = (n_ & 7) * 64 + (n_ >> 3);
  const int bh = o_ >> 3;
  const int q0 = (o_ & 7) * 128;
  const int tid = threadIdx.x, wave = tid >> 6, lane = tid & 63;
  const int l31 = lane & 31, hi = lane >> 5;
  const int qq = wave & 3, kvh = wave >> 2;

  __shared__ unsigned short SM[28672];

  const unsigned short* Kbase = Kt + (size_t)bh * SS * DAUG;
  const unsigned short* Vbase = VpT + (size_t)bh * 64 * 1024;

  bf16x8 qf[10];
  {
    const unsigned short* Qg = Qt + ((size_t)bh * SS + q0 + qq * 32 + l31) * DAUG + hi * 8;
#pragma unroll
    for (int kk = 0; kk < 10; ++kk) qf[kk] = *(const bf16x8*)(Qg + kk * 16);
  }

  auto stageK = [&](int kv0, int buf) {
    const unsigned short* Kg = Kbase + (size_t)kv0 * DAUG;
#pragma unroll
    for (int j = 0; j < 2; ++j) {
      int ibase = j * 512 + wave * 64;
      int i = ibase + lane;
      int row = i / 20, c = i % 20;
      async16(Kg + (size_t)row * DAUG + ksw(c, row) * 8, SM + buf * 10240 + (size_t)ibase * 8);
    }
    if (wave < 4) {
      int ibase = 1024 + wave * 64;
      int i = ibase + lane;
      int row = i / 20, c = i % 20;
      async16(Kg + (size_t)row * DAUG + ksw(c, row) * 8, SM + buf * 10240 + (size_t)ibase * 8);
    }
  };
  auto stageV = [&](int kv0, int buf) {
    int c = tid;
    int row = c >> 3, c8 = c & 7;
    async16(Vbase + (size_t)row * 1024 + kv0 + ((c8 ^ (row & 7)) << 3),
            SM + 20480 + buf * 4096 + (size_t)c * 8);
  };

  stageK(0, 0);
  stageV(0, 0);
  __syncthreads();

  f32x16 accO[2];
#pragma unroll
  for (int j = 0; j < 16; ++j) { accO[0][j] = 0.f; accO[1][j] = 0.f; }
  float run_m = -INFINITY, run_l = 0.f;

  const int krow = kvh * 32 + l31;

  for (int t = 0; t < 16; ++t) {
    const int cur = t & 1, nxt = cur ^ 1;
    if (t < 15) {
      stageK((t + 1) * 64, nxt);
      stageV((t + 1) * 64, nxt);
    }

    f32x16 sT;
#pragma unroll
    for (int j = 0; j < 16; ++j) sT[j] = 0.f;
    __builtin_amdgcn_s_setprio(1);
#pragma unroll
    for (int kk = 0; kk < 10; ++kk) {
      int c = 2 * kk + hi;
      bf16x8 kf = *(const bf16x8*)(SM + cur * 10240 + (size_t)krow * 160 + ksw(c, krow) * 8);
      sT = __builtin_amdgcn_mfma_f32_32x32x16_bf16(kf, qf[kk], sT, 0, 0, 0);
    }
    __builtin_amdgcn_s_setprio(0);

    float a0 = fmaxf(fmaxf(sT[0], sT[1]), sT[2]);
    float a1 = fmaxf(fmaxf(sT[3], sT[4]), sT[5]);
    float a2 = fmaxf(fmaxf(sT[6], sT[7]), sT[8]);
    float a3 = fmaxf(fmaxf(sT[9], sT[10]), sT[11]);
    float a4 = fmaxf(fmaxf(sT[12], sT[13]), sT[14]);
    float b0 = fmaxf(fmaxf(a0, a1), a2);
    float b1 = fmaxf(fmaxf(a3, a4), sT[15]);
    float mx = fmaxf(b0, b1);
    mx = fmaxf(mx, __shfl_xor(mx, 32, 64));

    bool cond = (mx <= run_m + 8.f);
    if (!__all(cond)) {
      float mnew = fmaxf(run_m, mx);
      float corr = exp2f(run_m - mnew);
      run_m = mnew;
      run_l *= corr;
#pragma unroll
      for (int j = 0; j < 16; ++j) { accO[0][j] *= corr; accO[1][j] *= corr; }
    }
    float lsum = 0.f;
#pragma unroll
    for (int j = 0; j < 16; ++j) {
      float p = exp2f(sT[j] - run_m);
      sT[j] = p;
      lsum += p;
    }
    run_l += lsum + __shfl_xor(lsum, 32, 64);

    uint32_t w[8];
#pragma unroll
    for (int j = 0; j < 8; ++j) w[j] = cvtpk(sT[2 * j], sT[2 * j + 1]);

    bf16x8 bfrag[2];
#pragma unroll
    for (int ks = 0; ks < 2; ++ks) {
      int b = ks * 4;
      uint32_t sel_a = hi ? w[b + 0] : w[b + 2];
      uint32_t sel_b = hi ? w[b + 1] : w[b + 3];
      uint32_t x_a = (uint32_t)__shfl_xor((int)sel_a, 32, 64);
      uint32_t x_b = (uint32_t)__shfl_xor((int)sel_b, 32, 64);
      union { uint32_t u[4]; bf16x8 v; } bw;
      bw.u[0] = hi ? x_a : w[b + 0];
      bw.u[1] = hi ? x_b : w[b + 1];
      bw.u[2] = hi ? w[b + 2] : x_a;
      bw.u[3] = hi ? w[b + 3] : x_b;
      bfrag[ks] = bw.v;
    }

    __builtin_amdgcn_s_setprio(1);
#pragma unroll
    for (int dt = 0; dt < 2; ++dt) {
      int vrow = dt * 32 + l31;
#pragma unroll
      for (int ks = 0; ks < 2; ++ks) {
        int c = kvh * 4 + ks * 2 + hi;
        bf16x8 vf = *(const bf16x8*)(SM + 20480 + cur * 4096 + (size_t)vrow * 64 +
                                     ((c ^ (vrow & 7)) << 3));
        accO[dt] = __builtin_amdgcn_mfma_f32_32x32x16_bf16(vf, bfrag[ks], accO[dt], 0, 0, 0);
      }
    }
    __builtin_amdgcn_s_setprio(0);

    __syncthreads();
  }

  float* SC = (float*)SM;
  float* Ml = SC + 8192;
  float* Ll = SC + 8320;
  uint32_t* OT = (uint32_t*)(SC + 8448);

  if (kvh == 1) {
#pragma unroll
    for (int dt = 0; dt < 2; ++dt)
#pragma unroll
      for (int j = 0; j < 16; ++j) {
        int d = (j & 3) + 8 * (j >> 2) + 4 * hi + 32 * dt;
        SC[qq * 2048 + d * 32 + l31] = accO[dt][j];
      }
    if (hi == 0) {
      Ml[qq * 32 + l31] = run_m;
      Ll[qq * 32 + l31] = run_l;
    }
  }
  __syncthreads();
  if (kvh == 0) {
    float m1 = Ml[qq * 32 + l31], l1v = Ll[qq * 32 + l31];
    float M = fmaxf(run_m, m1);
    float c0 = exp2f(run_m - M), c1 = exp2f(m1 - M);
    float inv = 1.f / (run_l * c0 + l1v * c1);
#pragma unroll
    for (int dt = 0; dt < 2; ++dt)
#pragma unroll
      for (int j = 0; j < 16; j += 2) {
        int d = (j & 3) + 8 * (j >> 2) + 4 * hi + 32 * dt;
        float o0 = (accO[dt][j] * c0 + SC[qq * 2048 + d * 32 + l31] * c1) * inv;
        float o1 = (accO[dt][j + 1] * c0 + SC[qq * 2048 + (d + 1) * 32 + l31] * c1) * inv;
        OT[(qq * 32 + l31) * 33 + (d >> 1)] = pk2(o0, o1);
      }
  }
  __syncthreads();
  for (int c = tid; c < 1024; c += 512) {
    int row = c >> 3, ch = c & 7;
    uint4 v;
    v.x = OT[row * 33 + ch * 4 + 0];
    v.y = OT[row * 33 + ch * 4 + 1];
    v.z = OT[row * 33 + ch * 4 + 2];
    v.w = OT[row * 33 + ch * 4 + 3];
    *(uint4*)(Oh + ((size_t)bh * SS + q0 + row) * 64 + ch * 8) = v;
  }
}

extern "C" void kernel_launch(void* const* d_in, const int* in_sizes, int n_in,
                              void* d_out, int out_size, void* d_ws, size_t ws_size,
                              hipStream_t stream) {
  const float* query = (const float*)d_in[0];
  const float* key = (const float*)d_in[1];
  const float* value = (const float*)d_in[2];
  const float* pe = (const float*)d_in[3];
  const float* pp = (const float*)d_in[4];
  const float* cpe = (const float*)d_in[5];
  const float* cpp = (const float*)d_in[6];
  const float* relq = (const float*)d_in[7];
  const float* relk = (const float*)d_in[8];
  const float* relv = (const float*)d_in[9];
  const float* Wq = (const float*)d_in[10];
  const float* Wk = (const float*)d_in[11];
  const float* Wv = (const float*)d_in[12];
  const float* Wo = (const float*)d_in[13];
  float* out = (float*)d_out;
  char* ws = (char*)d_ws;

  unsigned short* Xq = (unsigned short*)(ws + 0);
  unsigned short* Xk = (unsigned short*)(ws + 8388608);
  unsigned short* Xv = (unsigned short*)(ws + 16777216);
  unsigned short* Wqb = (unsigned short*)(ws + 25165824);
  unsigned short* Wkb = (unsigned short*)(ws + 27262976);
  unsigned short* Wvb = (unsigned short*)(ws + 29360128);
  unsigned short* Wob = (unsigned short*)(ws + 31457280);
  unsigned short* Qt = (unsigned short*)(ws + 33554432);
  unsigned short* Kt = (unsigned short*)(ws + 54525952);
  unsigned short* Vp = (unsigned short*)(ws + 75497472);
  unsigned short* Oh = (unsigned short*)(ws + 0);         // alias Xq (dead after proj)
  unsigned short* VpT = (unsigned short*)(ws + 8388608);  // alias Xk/Xv (dead after proj)

  convert7<<<dim3(1024, 7, 1), 256, 0, stream>>>(query, key, value, Wq, Wk, Wv, Wo, Xq, Xk, Xv,
                                                 Wqb, Wkb, Wvb, Wob);
  proj_qkv<<<dim3(32, 8, 3), 256, 0, stream>>>(Xq, Xk, Xv, Wqb, Wkb, Wvb, Qt, Kt, Vp, relk, relq);
  pos_vp<<<dim3(16, 64, 2), 256, 0, stream>>>(Qt, Kt, cpe, cpp, pe, pp, Vp, relv, VpT);
  flash_attn5<<<dim3(8, 64, 1), 512, 0, stream>>>(Qt, Kt, VpT, Oh);
  gemm_out<<<dim3(64, 8, 1), 256, 0, stream>>>(Oh, Wob, out);
}